// Round 18
// baseline (180.013 us; speedup 1.0000x reference)
//
#include <hip/hip_runtime.h>
#include <hip/hip_bf16.h>

typedef __bf16 bf16;
typedef __bf16 bf16x8 __attribute__((ext_vector_type(8)));
typedef __bf16 bf16x4 __attribute__((ext_vector_type(4)));
typedef __bf16 bf16x2 __attribute__((ext_vector_type(2)));
typedef float f32x4 __attribute__((ext_vector_type(4)));
typedef int int4v __attribute__((ext_vector_type(4)));
typedef int int2v __attribute__((ext_vector_type(2)));

#define DEV static __device__ __forceinline__

DEV void gload16(const void* g, void* l) {
    __builtin_amdgcn_global_load_lds(
        (const __attribute__((address_space(1))) void*)g,
        (__attribute__((address_space(3))) void*)l, 16, 0, 0);
}

DEV f32x4 mfma16(bf16x8 a, bf16x8 b, f32x4 c) {
    return __builtin_amdgcn_mfma_f32_16x16x32_bf16(a, b, c, 0, 0, 0);
}

DEV int cvtpk(float lo, float hi) {
    int r;
    asm("v_cvt_pk_bf16_f32 %0, %1, %2" : "=v"(r) : "v"(lo), "v"(hi));
    return r;
}

DEV float rexp2(float x) {   // raw v_exp_f32 (no denormal guard)
    float r;
    asm("v_exp_f32 %0, %1" : "=v"(r) : "v"(x));
    return r;
}

// ---------------------------------------------------------------
// Fused first-stage: blocks 0..255 = transpose+LN1 (h = LN(x^T));
// blocks 256..3327 = the 4 weight transposes (fp32 [K][N] -> bf16 [N][K]).
__global__ __launch_bounds__(512, 2)
void k_pre(const float* __restrict__ x, const float* __restrict__ gg,
           const float* __restrict__ bb, bf16* __restrict__ h,
           const float* __restrict__ w0, const float* __restrict__ w1,
           const float* __restrict__ w2, const float* __restrict__ w3,
           bf16* __restrict__ d0, bf16* __restrict__ d1,
           bf16* __restrict__ d2, bf16* __restrict__ d3) {
    __shared__ char sm[35840];
    int bid = blockIdx.x;
    int t = threadIdx.x;

    if (bid >= 256) {
        float* tile = (float*)sm;              // [32][33]
        int tt = bid - 256;
        const float* w;
        bf16* d;
        int K, N, ti;
        if (tt < 768)       { w = w0; d = d0; K = 512;  N = 1536; ti = tt; }
        else if (tt < 1024) { w = w1; d = d1; K = 512;  N = 512;  ti = tt - 768; }
        else if (tt < 2048) { w = w2; d = d2; K = 512;  N = 2048; ti = tt - 1024; }
        else                { w = w3; d = d3; K = 2048; N = 512;  ti = tt - 2048; }
        int ntn = N >> 5;
        int kt = ti / ntn, ntile = ti % ntn;
        int k0 = kt * 32, n0 = ntile * 32;
        int nl = t & 31, kl = t >> 5;
#pragma unroll
        for (int i = 0; i < 2; i++) {
            int k = kl + i * 16;
            tile[k * 33 + nl] = w[(size_t)(k0 + k) * N + n0 + nl];
        }
        __syncthreads();
        int kl2 = t & 31, nl2 = t >> 5;
#pragma unroll
        for (int i = 0; i < 2; i++) {
            int n = nl2 + i * 16;
            d[(size_t)(n0 + n) * K + k0 + kl2] = (bf16)tile[kl2 * 33 + n];
        }
        return;
    }

    bf16* big = (bf16*)sm;                     // [32][524]
    float* red = (float*)(sm + 33536);         // [8][32][2]
    float* mures = (float*)(sm + 35584);       // [32][2]
    int nt = bid & 127, b = bid >> 7;
    int n0 = nt * 32;

    int n = t & 31, cg = t >> 5;
    const float* xp = x + (size_t)b * 512 * 4096 +
                      (size_t)(cg * 32) * 4096 + n0 + n;
    float s = 0.f, ss = 0.f;
#pragma unroll
    for (int i = 0; i < 32; i++) {
        float v = xp[(size_t)i * 4096];
        s += v;
        ss += v * v;
        big[n * 524 + cg * 32 + i] = (bf16)v;
    }
    s += __shfl_xor(s, 32);
    ss += __shfl_xor(ss, 32);
    int w = t >> 6, l = t & 63;
    if (l < 32) {
        red[(w * 32 + n) * 2] = s;
        red[(w * 32 + n) * 2 + 1] = ss;
    }
    __syncthreads();
    if (t < 32) {
        float ts = 0.f, tss = 0.f;
#pragma unroll
        for (int ww = 0; ww < 8; ww++) {
            ts += red[(ww * 32 + t) * 2];
            tss += red[(ww * 32 + t) * 2 + 1];
        }
        float mu = ts * (1.f / 512.f);
        float var = tss * (1.f / 512.f) - mu * mu;
        mures[t * 2] = mu;
        mures[t * 2 + 1] = rsqrtf(var + 1e-5f);
    }
    __syncthreads();

    int nw = t >> 4, cs = t & 15;
    float mu = mures[nw * 2], rs = mures[nw * 2 + 1];
    bf16* hd = h + (size_t)(b * 4096 + n0 + nw) * 512;
#pragma unroll
    for (int j = 0; j < 4; j++) {
        int c = cs * 8 + j * 128;
        bf16x8 vv = *(const bf16x8*)&big[nw * 524 + c];
        f32x4 g0v = *(const f32x4*)(gg + c);
        f32x4 g1v = *(const f32x4*)(gg + c + 4);
        f32x4 b0v = *(const f32x4*)(bb + c);
        f32x4 b1v = *(const f32x4*)(bb + c + 4);
        bf16x8 o;
#pragma unroll
        for (int k = 0; k < 4; k++) {
            o[k] = (bf16)(((float)vv[k] - mu) * rs * g0v[k] + b0v[k]);
            o[k + 4] = (bf16)(((float)vv[k + 4] - mu) * rs * g1v[k] + b1v[k]);
        }
        *(bf16x8*)(hd + c) = o;
    }
}

// ---------------------------------------------------------------
// Fused residual + transpose + LayerNorm: h[n][c] = LN_c(x^T + po).
__global__ __launch_bounds__(512, 2)
void k_tln2(const float* __restrict__ x, const bf16* __restrict__ po,
            const float* __restrict__ gg, const float* __restrict__ bb,
            bf16* __restrict__ h) {
    __shared__ char sm[69632];
    bf16* big = (bf16*)sm;                     // [32][524]
    float* red = (float*)(sm + 33536);         // [8][32][2]
    float* mures = (float*)(sm + 35584);       // [32][2]
    bf16* pob = (bf16*)(sm + 35840);           // [32][524]

    int t = threadIdx.x;
    int bid = blockIdx.x;
    int nt = bid & 127, b = bid >> 7;
    int n0 = nt * 32;

    {
        int rr = t >> 4, cs16 = t & 15;
        const bf16* ps = po + (size_t)(b * 4096 + n0 + rr) * 512 + cs16 * 32;
#pragma unroll
        for (int j = 0; j < 4; j++)
            *(bf16x8*)&pob[rr * 524 + cs16 * 32 + j * 8] =
                *(const bf16x8*)(ps + j * 8);
        __syncthreads();
    }

    int n = t & 31, cg = t >> 5;
    const float* xp = x + (size_t)b * 512 * 4096 +
                      (size_t)(cg * 32) * 4096 + n0 + n;
    float s = 0.f, ss = 0.f;
#pragma unroll
    for (int i = 0; i < 32; i++) {
        float v = xp[(size_t)i * 4096] + (float)pob[n * 524 + cg * 32 + i];
        s += v;
        ss += v * v;
        big[n * 524 + cg * 32 + i] = (bf16)v;
    }
    s += __shfl_xor(s, 32);
    ss += __shfl_xor(ss, 32);
    int w = t >> 6, l = t & 63;
    if (l < 32) {
        red[(w * 32 + n) * 2] = s;
        red[(w * 32 + n) * 2 + 1] = ss;
    }
    __syncthreads();
    if (t < 32) {
        float ts = 0.f, tss = 0.f;
#pragma unroll
        for (int ww = 0; ww < 8; ww++) {
            ts += red[(ww * 32 + t) * 2];
            tss += red[(ww * 32 + t) * 2 + 1];
        }
        float mu = ts * (1.f / 512.f);
        float var = tss * (1.f / 512.f) - mu * mu;
        mures[t * 2] = mu;
        mures[t * 2 + 1] = rsqrtf(var + 1e-5f);
    }
    __syncthreads();

    int nw = t >> 4, cs = t & 15;
    float mu = mures[nw * 2], rs = mures[nw * 2 + 1];
    bf16* hd = h + (size_t)(b * 4096 + n0 + nw) * 512;
#pragma unroll
    for (int j = 0; j < 4; j++) {
        int c = cs * 8 + j * 128;
        bf16x8 vv = *(const bf16x8*)&big[nw * 524 + c];
        f32x4 g0v = *(const f32x4*)(gg + c);
        f32x4 g1v = *(const f32x4*)(gg + c + 4);
        f32x4 b0v = *(const f32x4*)(bb + c);
        f32x4 b1v = *(const f32x4*)(bb + c + 4);
        bf16x8 o;
#pragma unroll
        for (int k = 0; k < 4; k++) {
            o[k] = (bf16)(((float)vv[k] - mu) * rs * g0v[k] + b0v[k]);
            o[k + 4] = (bf16)(((float)vv[k + 4] - mu) * rs * g1v[k] + b1v[k]);
        }
        *(bf16x8*)(hd + c) = o;
    }
}

// ---------------------------------------------------------------
// GEMM (2-phase): out[M][N](bf16) = A @ BT^T + bias.
// MODE 0 plain / 2 qkv (V-slice transposed into vt) / 3 ffn2+final.
template <int MODE, int BN>
__global__ __launch_bounds__(256, BN == 64 ? 3 : 2)
void k_gemm(const bf16* __restrict__ A, const bf16* __restrict__ BT,
            const float* __restrict__ bias, bf16* __restrict__ outb,
            bf16* __restrict__ vtout, const float* __restrict__ xin,
            const bf16* __restrict__ poin, float* __restrict__ yout,
            int M, int N, int K) {
    constexpr int CG = BN / 32;
    constexpr int BSZ = CG * 4096;
    __shared__ char smem[32768 + 2 * BSZ];
    int ntn = N / BN;
    int nwg = gridDim.x;
    int bid = blockIdx.x;
    int cpx = nwg >> 3;
    bid = (bid & 7) * cpx + (bid >> 3);       // XCD-aware swizzle
    int bm = bid / ntn, bn = bid % ntn;
    int m0 = bm * 128, n0 = bn * BN;
    int tid = threadIdx.x;
    int w = tid >> 6, l = tid & 63;
    int wm = w >> 1, wn = w & 1;
    int l15 = l & 15, lg = l >> 4;

    f32x4 acc[4][CG];
#pragma unroll
    for (int i = 0; i < 4; i++)
#pragma unroll
        for (int j = 0; j < CG; j++) acc[i][j] = (f32x4){0.f, 0.f, 0.f, 0.f};

    int srow = tid >> 3, sphys = tid & 7;
    int lrow_a = wm * 64 + l15;
    int lrow_b = wn * (BN / 2) + l15;

#define GEMM_STAGE(k0v, bb)                                                  \
    do {                                                                     \
        _Pragma("unroll") for (int s = 0; s < 4; s++) {                      \
            int row = s * 32 + srow;                                         \
            int k16 = sphys ^ (row & 7);                                     \
            gload16(A + (size_t)(m0 + row) * K + (k0v) + k16 * 8,            \
                    smem + (bb) * 16384 + s * 4096 + tid * 16);              \
        }                                                                    \
        _Pragma("unroll") for (int s = 0; s < CG; s++) {                     \
            int row = s * 32 + srow;                                         \
            int k16 = sphys ^ (row & 7);                                     \
            gload16(BT + (size_t)(n0 + row) * K + (k0v) + k16 * 8,           \
                    smem + 32768 + (bb) * BSZ + s * 4096 + tid * 16);        \
        }                                                                    \
    } while (0)

    int nk = K >> 6;
    GEMM_STAGE(0, 0);
    int cur = 0;
    for (int kt = 0; kt < nk; kt++) {
        if (kt + 1 < nk) {
            GEMM_STAGE((kt + 1) << 6, cur ^ 1);
            if constexpr (BN == 128)
                asm volatile("s_waitcnt vmcnt(8)" ::: "memory");
            else
                asm volatile("s_waitcnt vmcnt(6)" ::: "memory");
        } else {
            asm volatile("s_waitcnt vmcnt(0)" ::: "memory");
        }
        __builtin_amdgcn_s_barrier();
        __builtin_amdgcn_sched_barrier(0);
        const char* pA = smem + cur * 16384;
        const char* pB = smem + 32768 + cur * BSZ;
#pragma unroll
        for (int ks = 0; ks < 2; ks++) {
            bf16x8 af[4], bfr[CG];
#pragma unroll
            for (int rg = 0; rg < 4; rg++) {
                int row = lrow_a + rg * 16;
                af[rg] = *(const bf16x8*)(pA + row * 128 +
                                          (((lg + ks * 4) ^ (row & 7)) << 4));
            }
#pragma unroll
            for (int cg = 0; cg < CG; cg++) {
                int row = lrow_b + cg * 16;
                bfr[cg] = *(const bf16x8*)(pB + row * 128 +
                                           (((lg + ks * 4) ^ (row & 7)) << 4));
            }
#pragma unroll
            for (int rg = 0; rg < 4; rg++)
#pragma unroll
                for (int cg = 0; cg < CG; cg++)
                    acc[rg][cg] = mfma16(af[rg], bfr[cg], acc[rg][cg]);
        }
        __builtin_amdgcn_s_barrier();
        cur ^= 1;
    }
#undef GEMM_STAGE

    if constexpr (MODE == 2) {
        if (n0 >= 1024) {
            char* vl = smem;        // col-major [BN col][136 row] bf16
#pragma unroll
            for (int cg = 0; cg < CG; cg++) {
                int col = wn * (BN / 2) + cg * 16 + l15;
                float bz = bias[n0 + col];
#pragma unroll
                for (int rg = 0; rg < 4; rg++) {
                    int rowb = wm * 64 + rg * 16 + lg * 4;
                    int2v qq = {cvtpk(acc[rg][cg][0] + bz, acc[rg][cg][1] + bz),
                                cvtpk(acc[rg][cg][2] + bz, acc[rg][cg][3] + bz)};
                    *(int2v*)(vl + col * 272 + rowb * 2) = qq;
                }
            }
            __syncthreads();
            int b = m0 >> 12, nrow0 = m0 & 4095;
            int dl = tid >> 3, c8 = tid & 7;
#pragma unroll
            for (int dd = 0; dd < BN / 32; dd++) {
                int d = dd * 32 + dl;
                int ch = (n0 - 1024) + d;
                bf16* dst = vtout +
                    ((size_t)((b * 8 + (ch >> 6)) * 64 + (ch & 63))) * 4096 + nrow0;
#pragma unroll
                for (int half = 0; half < 2; half++) {
                    int chunk = half * 8 + c8;
                    bf16x8 vv = *(const bf16x8*)(vl + d * 272 + chunk * 16);
                    *(bf16x8*)(dst + chunk * 8) = vv;
                }
            }
            return;
        }
    }

    if constexpr (MODE == 3) {
        // ---- fused final: y[b][c][n] = 2x + po + (acc + bias)
        float* ts = (float*)smem;            // [64 c][132 n] fp32
        int b = m0 >> 12, nrow0 = m0 & 4095;
#pragma unroll
        for (int cg = 0; cg < CG; cg++) {
            int lcol = wn * (BN / 2) + cg * 16 + l15;
            float bz = bias[n0 + lcol];
#pragma unroll
            for (int rg = 0; rg < 4; rg++) {
#pragma unroll
                for (int j = 0; j < 4; j++) {
                    int lrow = wm * 64 + rg * 16 + lg * 4 + j;
                    float v = acc[rg][cg][j] + bz +
                        (float)poin[(size_t)(m0 + lrow) * 512 + n0 + lcol];
                    ts[lcol * 132 + lrow] = v;
                }
            }
        }
        __syncthreads();
        int nl = (tid & 31) * 4, chh = tid >> 5;
#pragma unroll
        for (int q = 0; q < 8; q++) {
            int c = chh + q * 8;
            size_t off = ((size_t)b * 512 + n0 + c) * 4096 + nrow0 + nl;
            f32x4 xv = *(const f32x4*)(xin + off);
            f32x4 tv = *(const f32x4*)&ts[c * 132 + nl];
            f32x4 ov;
#pragma unroll
            for (int k2 = 0; k2 < 4; k2++) ov[k2] = 2.f * xv[k2] + tv[k2];
            *(f32x4*)(yout + off) = ov;
        }
        return;
    }

    constexpr int RS = BN * 2 + 8;
    constexpr int CH = BN / 8;
    char* ep = smem;
#pragma unroll
    for (int cg = 0; cg < CG; cg++) {
        int lcol = wn * (BN / 2) + cg * 16 + l15;
        float bz = bias[n0 + lcol];
#pragma unroll
        for (int rg = 0; rg < 4; rg++) {
#pragma unroll
            for (int j = 0; j < 4; j++) {
                int lrow = wm * 64 + rg * 16 + lg * 4 + j;
                float v = acc[rg][cg][j] + bz;
                *(bf16*)(ep + lrow * RS + lcol * 2) = (bf16)v;
            }
        }
    }
    __syncthreads();
    int cch = tid & (CH - 1);
    int rof = tid / CH;
    constexpr int RPP = 256 / CH;
#pragma unroll
    for (int i = 0; i < 128 / RPP; i++) {
        int row = i * RPP + rof;
        bf16x8 vv = *(const bf16x8*)(ep + row * RS + cch * 16);
        *(bf16x8*)(outb + (size_t)(m0 + row) * N + n0 + cch * 8) = vv;
    }
}

// ---------------------------------------------------------------
// FFN1 GEMM, 8-phase 256^2 schedule (T3+T4): M=8192 N=2048 K=512, relu.
__global__ __launch_bounds__(512, 2)
void k_gemm8(const bf16* __restrict__ A, const bf16* __restrict__ BT,
             const float* __restrict__ bias, bf16* __restrict__ outb) {
    __shared__ char sL[131072];   // A: [2buf][2s][256r][64B] @0; B same @65536
    int bid = blockIdx.x;
    bid = (bid & 7) * 32 + (bid >> 3);        // XCD swizzle (grid 256)
    int bm = bid >> 3, bn = bid & 7;
    int m0 = bm * 256, n0 = bn * 256;
    int tid = threadIdx.x;
    int w = tid >> 6, l = tid & 63;
    int wm = w >> 2, wn = w & 3;              // 2M x 4N waves
    int l15 = l & 15, lg = l >> 4;
    int cpr = (lg ^ ((l15 >> 1) & 3)) << 4;   // read chunk byte-offset (lane-inv)

    f32x4 acc[8][4];
#pragma unroll
    for (int i = 0; i < 8; i++)
#pragma unroll
        for (int j = 0; j < 4; j++) acc[i][j] = (f32x4){0.f, 0.f, 0.f, 0.f};

    int srow = tid >> 2, scp = tid & 3;
    int kofs = (scp ^ ((srow >> 1) & 3)) * 8;
    const bf16* gA0 = A + (size_t)(m0 + srow) * 512 + kofs;
    const bf16* gA1 = gA0 + 128 * 512;
    const bf16* gB0 = BT + (size_t)(n0 + srow) * 512 + kofs;
    const bf16* gB1 = gB0 + 128 * 512;
    char* dA = sL + tid * 16;
    char* dB = sL + 65536 + tid * 16;
    const char* pA0 = sL + (wm * 128 + l15) * 64 + cpr;
    const char* pB0 = sL + 65536 + (wn * 64 + l15) * 64 + cpr;

#define STGA(T, S, BUF)                                                       \
    gload16(gA0 + (T) * 64 + (S) * 32, dA + (BUF) * 32768 + (S) * 16384);     \
    gload16(gA1 + (T) * 64 + (S) * 32, dA + (BUF) * 32768 + (S) * 16384 + 8192);
#define STGB(T, S, BUF)                                                       \
    gload16(gB0 + (T) * 64 + (S) * 32, dB + (BUF) * 32768 + (S) * 16384);     \
    gload16(gB1 + (T) * 64 + (S) * 32, dB + (BUF) * 32768 + (S) * 16384 + 8192);
#define WB8 asm volatile("s_waitcnt vmcnt(8)" ::: "memory"); __builtin_amdgcn_s_barrier();
#define WB4 asm volatile("s_waitcnt vmcnt(4)" ::: "memory"); __builtin_amdgcn_s_barrier();
#define WB0 asm volatile("s_waitcnt vmcnt(0)" ::: "memory"); __builtin_amdgcn_s_barrier();
#define WBN

    bf16x8 bfr[4];

#define PH(BUF, S, RGH, WAITC, STGC)                                          \
    {                                                                         \
        WAITC                                                                 \
        if ((RGH) == 0) {                                                     \
            _Pragma("unroll") for (int cg = 0; cg < 4; cg++)                  \
                bfr[cg] = *(const bf16x8*)(pB0 + (BUF) * 32768 +              \
                                           (S) * 16384 + cg * 1024);          \
        }                                                                     \
        bf16x8 af[4];                                                         \
        _Pragma("unroll") for (int i = 0; i < 4; i++)                         \
            af[i] = *(const bf16x8*)(pA0 + (BUF) * 32768 + (S) * 16384 +      \
                                     ((RGH) * 4 + i) * 1024);                 \
        STGC                                                                  \
        __builtin_amdgcn_s_barrier();                                         \
        asm volatile("s_waitcnt lgkmcnt(0)" ::: "memory");                    \
        __builtin_amdgcn_sched_barrier(0);                                    \
        __builtin_amdgcn_s_setprio(1);                                        \
        _Pragma("unroll") for (int i = 0; i < 4; i++)                         \
            _Pragma("unroll") for (int cg = 0; cg < 4; cg++)                  \
                acc[(RGH) * 4 + i][cg] =                                      \
                    mfma16(af[i], bfr[cg], acc[(RGH) * 4 + i][cg]);           \
        __builtin_amdgcn_s_setprio(0);                                        \
    }

#define TILEF(T, BUF)                                                         \
    PH(BUF, 0, 0, WB8, STGA(T + 1, 1, BUF ^ 1))                               \
    PH(BUF, 0, 1, WBN, STGB(T + 1, 1, BUF ^ 1))                               \
    PH(BUF, 1, 0, WB8, STGA(T + 2, 0, BUF))                                   \
    PH(BUF, 1, 1, WBN, STGB(T + 2, 0, BUF))

    STGA(0, 0, 0) STGB(0, 0, 0) STGA(0, 1, 0) STGB(0, 1, 0)
    STGA(1, 0, 1) STGB(1, 0, 1)

    TILEF(0, 0) TILEF(1, 1) TILEF(2, 0) TILEF(3, 1) TILEF(4, 0) TILEF(5, 1)
    PH(0, 0, 0, WB8, STGA(7, 1, 1))
    PH(0, 0, 1, WBN, STGB(7, 1, 1))
    PH(0, 1, 0, WB8, )
    PH(0, 1, 1, WBN, )
    PH(1, 0, 0, WB4, )
    PH(1, 0, 1, WBN, )
    PH(1, 1, 0, WB0, )
    PH(1, 1, 1, WBN, )
#undef TILEF
#undef PH
#undef WB8
#undef WB4
#undef WB0
#undef WBN
#undef STGA
#undef STGB

    // epilogue: relu + 2-pass LDS bounce (rows 0-127, 128-255)
    float bz[4];
#pragma unroll
    for (int cg = 0; cg < 4; cg++) bz[cg] = bias[n0 + wn * 64 + cg * 16 + l15];
#pragma unroll
    for (int h2 = 0; h2 < 2; h2++) {
        __syncthreads();
        if (wm == h2) {
#pragma unroll
            for (int rg = 0; rg < 8; rg++)
#pragma unroll
                for (int cg = 0; cg < 4; cg++)
#pragma unroll
                    for (int j = 0; j < 4; j++) {
                        int rl = rg * 16 + lg * 4 + j;
                        int cl = wn * 64 + cg * 16 + l15;
                        float v = fmaxf(acc[rg][cg][j] + bz[cg], 0.f);
                        *(bf16*)(sL + rl * 520 + cl * 2) = (bf16)v;
                    }
        }
        __syncthreads();
        int cch = tid & 31, rof = tid >> 5;
#pragma unroll
        for (int p = 0; p < 8; p++) {
            int row = p * 16 + rof;
            bf16x8 vv = *(const bf16x8*)(sL + row * 520 + cch * 16);
            *(bf16x8*)(outb + (size_t)(m0 + h2 * 128 + row) * 2048 +
                       n0 + cch * 8) = vv;
        }
    }
}

// ---------------------------------------------------------------
// Flash attention v13: split-KV. Each block handles 32 KV tiles (half the
// range) -> grid 1024 = 4 blocks/CU = 8 waves/SIMD (4 independent barrier
// groups per CU; MFMA/VALU phases of different blocks interleave). m==0
// softmax -> partials combine by simple addition: unnormalized O (bf16) +
// lsum (f32) written per block; k_comb normalizes. LDS 32KB x 4 = 128KB.
__global__ __launch_bounds__(512, 8)
void k_attn(const bf16* __restrict__ qkvb, const bf16* __restrict__ vt,
            bf16* __restrict__ part, float* __restrict__ lpart) {
    __shared__ bf16 sK[2][64 * 64];
    __shared__ bf16 sV[2][64 * 64];
    const float sc = 0.044194173824159216f * 1.4426950408889634f; // 1/sqrt(512)*log2e
    int bid = blockIdx.x;
    int nb2 = (bid & 7) * 128 + (bid >> 3);   // XCD swizzle (grid 1024)
    int nb = nb2 >> 1, half = nb2 & 1;
    int bh = nb >> 5, qt = nb & 31;
    int b = bh >> 3, hh = bh & 7;
    int q0 = qt * 128;
    int tid = threadIdx.x, w = tid >> 6, l = tid & 63;
    int l15 = l & 15, lg = l >> 4, l7 = l15 & 7;
    int vperm = ((lg & 1) << 1) | (lg >> 1);
    const bf16* qbase = qkvb + (size_t)b * 4096 * 1536 + hh * 64;
    const bf16* kbase = qbase + 512;
    const bf16* vbase = vt + (size_t)bh * 64 * 4096;
    int srow = tid >> 3, sphys = tid & 7;

    const char* kp0 = (const char*)&sK[0][0] + l15 * 128 + ((lg ^ l7) << 4);
    const char* kp1 = (const char*)&sK[0][0] + l15 * 128 + (((4 + lg) ^ l7) << 4);
    const char* vp0 = (const char*)&sV[0][0] + l15 * 128 + ((vperm ^ l7) << 4);
    const char* vp1 = (const char*)&sV[0][0] + l15 * 128 + (((4 + vperm) ^ l7) << 4);
    char* dK0 = (char*)&sK[0][0] + tid * 16;
    char* dV0 = (char*)&sV[0][0] + tid * 16;
    const char* kg = (const char*)(kbase +
        (size_t)(half * 2048 + srow) * 1536 + (sphys ^ (srow & 7)) * 8);
    const char* vg = (const char*)(vbase + (size_t)srow * 4096 +
        half * 2048 + (sphys ^ (srow & 7)) * 8);

    gload16(kg, dK0);
    gload16(vg, dV0);
    kg += 196608;
    vg += 128;

    bf16x8 qf[2];
#pragma unroll
    for (int ks = 0; ks < 2; ks++) {
        bf16x8 v = *(const bf16x8*)(qbase +
            (size_t)(q0 + w * 16 + l15) * 1536 + ks * 32 + lg * 8);
        bf16x8 o;
#pragma unroll
        for (int j = 0; j < 8; j++) o[j] = (bf16)((float)v[j] * sc);
        qf[ks] = o;
    }
    bf16x8 ones;
#pragma unroll
    for (int j = 0; j < 8; j++) ones[j] = (bf16)1.0f;

    const f32x4 kZ = {0.f, 0.f, 0.f, 0.f};
    f32x4 accl = kZ;
    f32x4 acc[4];
#pragma unroll
    for (int df = 0; df < 4; df++) acc[df] = kZ;

#define ABODY(BUF, PF)                                                        \
    {                                                                         \
        if (PF) {                                                             \
            gload16(kg, dK0 + (1 - (BUF)) * 8192);                            \
            gload16(vg, dV0 + (1 - (BUF)) * 8192);                            \
            kg += 196608;                                                     \
            vg += 128;                                                        \
            asm volatile("s_waitcnt vmcnt(2)" ::: "memory");                  \
        } else {                                                              \
            asm volatile("s_waitcnt vmcnt(0)" ::: "memory");                  \
        }                                                                     \
        __builtin_amdgcn_s_barrier();                                         \
        __builtin_amdgcn_sched_barrier(0);                                    \
        f32x4 s0, s1, s2, s3;                                                 \
        __builtin_amdgcn_s_setprio(1);                                        \
        s0 = mfma16(*(const bf16x8*)(kp0 + (BUF) * 8192 + 0 * 2048), qf[0], kZ); \
        s0 = mfma16(*(const bf16x8*)(kp1 + (BUF) * 8192 + 0 * 2048), qf[1], s0); \
        s1 = mfma16(*(const bf16x8*)(kp0 + (BUF) * 8192 + 1 * 2048), qf[0], kZ); \
        s1 = mfma16(*(const bf16x8*)(kp1 + (BUF) * 8192 + 1 * 2048), qf[1], s1); \
        __builtin_amdgcn_s_setprio(0);                                        \
        float e0 = rexp2(s0[0]), e1 = rexp2(s0[1]);                           \
        float e2 = rexp2(s0[2]), e3 = rexp2(s0[3]);                           \
        float e4 = rexp2(s1[0]), e5 = rexp2(s1[1]);                           \
        float e6 = rexp2(s1[2]), e7 = rexp2(s1[3]);                           \
        __builtin_amdgcn_s_setprio(1);                                        \
        s2 = mfma16(*(const bf16x8*)(kp0 + (BUF) * 8192 + 2 * 2048), qf[0], kZ); \
        s2 = mfma16(*(const bf16x8*)(kp1 + (BUF) * 8192 + 2 * 2048), qf[1], s2); \
        s3 = mfma16(*(const bf16x8*)(kp0 + (BUF) * 8192 + 3 * 2048), qf[0], kZ); \
        s3 = mfma16(*(const bf16x8*)(kp1 + (BUF) * 8192 + 3 * 2048), qf[1], s3); \
        __builtin_amdgcn_s_setprio(0);                                        \
        int p0 = cvtpk(e0, e1), p1 = cvtpk(e2, e3);                           \
        int p2 = cvtpk(e4, e5), p3 = cvtpk(e6, e7);                           \
        asm("v_permlane16_swap_b32 %0, %1" : "+v"(p2), "+v"(p0));             \
        asm("v_permlane16_swap_b32 %0, %1" : "+v"(p3), "+v"(p1));             \
        {                                                                     \
            int4v ai = {p0, p1, p2, p3};                                      \
            bf16x8 af = __builtin_bit_cast(bf16x8, ai);                       \
            __builtin_amdgcn_s_setprio(1);                                    \
            acc[0] = mfma16(af, *(const bf16x8*)(vp0 + (BUF) * 8192 + 0 * 2048), acc[0]); \
            acc[1] = mfma16(af, *(const bf16x8*)(vp0 + (BUF) * 8192 + 1 * 2048), acc[1]); \
            acc[2] = mfma16(af, *(const bf16x8*)(vp0 + (BUF) * 8192 + 2 * 2048), acc[2]); \
            acc[3] = mfma16(af, *(const bf16x8*)(vp0 + (BUF) * 8192 + 3 * 2048), acc[3]); \
            accl = mfma16(af, ones, accl);                                    \
            __builtin_amdgcn_s_setprio(0);                                    \
        }                                                                     \
        float e8 = rexp2(s2[0]), e9 = rexp2(s2[1]);                           \
        float e10 = rexp2(s2[2]), e11 = rexp2(s2[3]);                         \
        float e12 = rexp2(s3[0]), e13 = rexp2(s3[1]);                         \
        float e14 = rexp2(s3[2]), e15 = rexp2(s3[3]);                         \
        int p4 = cvtpk(e8, e9), p5 = cvtpk(e10, e11);                         \
        int p6 = cvtpk(e12, e13), p7 = cvtpk(e14, e15);                       \
        asm("v_permlane16_swap_b32 %0, %1" : "+v"(p6), "+v"(p4));             \
        asm("v_permlane16_swap_b32 %0, %1" : "+v"(p7), "+v"(p5));             \
        {                                                                     \
            int4v ai = {p4, p5, p6, p7};                                      \
            bf16x8 af = __builtin_bit_cast(bf16x8, ai);                       \
            __builtin_amdgcn_s_setprio(1);                                    \
            acc[0] = mfma16(af, *(const bf16x8*)(vp1 + (BUF) * 8192 + 0 * 2048), acc[0]); \
            acc[1] = mfma16(af, *(const bf16x8*)(vp1 + (BUF) * 8192 + 1 * 2048), acc[1]); \
            acc[2] = mfma16(af, *(const bf16x8*)(vp1 + (BUF) * 8192 + 2 * 2048), acc[2]); \
            acc[3] = mfma16(af, *(const bf16x8*)(vp1 + (BUF) * 8192 + 3 * 2048), acc[3]); \
            accl = mfma16(af, ones, accl);                                    \
            __builtin_amdgcn_s_setprio(0);                                    \
        }                                                                     \
        __builtin_amdgcn_s_barrier();                                         \
    }

    for (int tt = 0; tt < 15; tt++) {
        ABODY(0, 1)
        ABODY(1, 1)
    }
    ABODY(0, 1)
    ABODY(1, 0)
#undef ABODY

    // ---- write unnormalized partial O (bf16, via coalescing bounce) + lsum
    bf16* ow = (bf16*)&sK[0][0] + w * 16 * 64;
#pragma unroll
    for (int df = 0; df < 4; df++) {
        int chunk = df * 2 + (l15 >> 3);
        int within = l15 & 7;
#pragma unroll
        for (int j = 0; j < 4; j++) {
            int q = lg * 4 + j;
            *(bf16*)((char*)ow + q * 128 + ((chunk ^ (q & 7)) << 4) + within * 2) =
                (bf16)acc[df][j];
        }
    }
    if (l15 == 0) {
#pragma unroll
        for (int j = 0; j < 4; j++)
            lpart[(size_t)nb2 * 128 + w * 16 + lg * 4 + j] = accl[j];
    }
    __syncthreads();
    const char* owr = (const char*)ow;
    bf16* pdst = part + (size_t)nb2 * 8192 + w * 16 * 64;
#pragma unroll
    for (int hf = 0; hf < 2; hf++) {
        int r = l >> 2, ch = (l & 3) + hf * 4;
        bf16x8 vv = *(const bf16x8*)(owr + r * 128 + ((ch ^ (r & 7)) << 4));
        *(bf16x8*)(pdst + r * 64 + ch * 8) = vv;
    }
}

// ---------------------------------------------------------------
// Combine split-KV partials: attno = (P0 + P1) / (l0 + l1).
__global__ __launch_bounds__(256)
void k_comb(const bf16* __restrict__ part, const float* __restrict__ lpart,
            bf16* __restrict__ attno) {
    int nb = blockIdx.x;
    int bh = nb >> 5, qt = nb & 31;
    int b = bh >> 3, hh = bh & 7;
    int q0 = qt * 128;
    int tid = threadIdx.x;
    int r = tid >> 1, dh = (tid & 1) * 32;
    const bf16* p0 = part + (size_t)nb * 2 * 8192 + r * 64 + dh;
    const bf16* p1 = p0 + 8192;
    float inv = 1.0f / (lpart[(size_t)nb * 256 + r] +
                        lpart[(size_t)nb * 256 + 128 + r]);
    bf16* dst = attno + (size_t)(b * 4096 + q0 + r) * 512 + hh * 64 + dh;
#pragma unroll
    for (int c4 = 0; c4 < 4; c4++) {
        bf16x8 a = *(const bf16x8*)(p0 + c4 * 8);
        bf16x8 bb8 = *(const bf16x8*)(p1 + c4 * 8);
        bf16x8 o;
#pragma unroll
        for (int j = 0; j < 8; j++)
            o[j] = (bf16)(((float)a[j] + (float)bb8[j]) * inv);
        *(bf16x8*)(dst + c4 * 8) = o;
    }
}

// ---------------------------------------------------------------
extern "C" void kernel_launch(void* const* d_in, const int* in_sizes, int n_in,
                              void* d_out, int out_size, void* d_ws, size_t ws_size,
                              hipStream_t stream) {
    const float* x = (const float*)d_in[0];
    const float* ln1g = (const float*)d_in[1];
    const float* ln1b = (const float*)d_in[2];
    const float* wqkv = (const float*)d_in[3];
    const float* bqkv = (const float*)d_in[4];
    const float* wproj = (const float*)d_in[5];
    const float* bproj = (const float*)d_in[6];
    const float* ln2g = (const float*)d_in[7];
    const float* ln2b = (const float*)d_in[8];
    const float* wffn1 = (const float*)d_in[9];
    const float* bffn1 = (const float*)d_in[10];
    const float* wffn2 = (const float*)d_in[11];
    const float* bffn2 = (const float*)d_in[12];
    float* y = (float*)d_out;

    char* ws = (char*)d_ws;
    bf16* po    = (bf16*)(ws + 0);            // 8.4M (written by proj, after comb)
    bf16* part  = (bf16*)(ws + 0);            // 16M attn partials (dead before po)
    bf16* h     = (bf16*)(ws + 16777216);     // h1 / attno / h2 (sequential)
    bf16* qkvb  = (bf16*)(ws + 25165824);     // 24M
    bf16* vtb   = (bf16*)(ws + 50331648);     // 8M
    bf16* f1    = (bf16*)(ws + 25165824);     // alias qkv+vt (dead after attn)
    bf16* wqT   = (bf16*)(ws + 58720256);     // dead after qkv GEMM
    float* lpart = (float*)(ws + 58720256);   // 512KB, overlays dead wqT
    bf16* wpT   = (bf16*)(ws + 60293120);
    bf16* w1T   = (bf16*)(ws + 60817408);
    bf16* w2T   = (bf16*)(ws + 62914560);
    bf16* attno = h;

    k_pre<<<3328, 512, 0, stream>>>(x, ln1g, ln1b, h,
                                    wqkv, wproj, wffn1, wffn2,
                                    wqT, wpT, w1T, w2T);
    k_gemm<2, 128><<<768, 256, 0, stream>>>(h, wqT, bqkv, qkvb, vtb,
                                            nullptr, nullptr, nullptr,
                                            8192, 1536, 512);
    k_attn<<<1024, 512, 0, stream>>>(qkvb, vtb, part, lpart);
    k_comb<<<512, 256, 0, stream>>>(part, lpart, attno);
    k_gemm<0, 64><<<512, 256, 0, stream>>>(attno, wpT, bproj, po, nullptr,
                                           nullptr, nullptr, nullptr,
                                           8192, 512, 512);
    k_tln2<<<256, 512, 0, stream>>>(x, po, ln2g, ln2b, h);
    k_gemm8<<<256, 512, 0, stream>>>(h, w1T, bffn1, f1);
    k_gemm<3, 64><<<512, 256, 0, stream>>>(f1, w2T, bffn2, nullptr, nullptr,
                                           x, po, y, 8192, 512, 2048);
}

// Round 19
// 171.948 us; speedup vs baseline: 1.0469x; 1.0469x over previous
//
#include <hip/hip_runtime.h>
#include <hip/hip_bf16.h>

typedef __bf16 bf16;
typedef __bf16 bf16x8 __attribute__((ext_vector_type(8)));
typedef __bf16 bf16x4 __attribute__((ext_vector_type(4)));
typedef __bf16 bf16x2 __attribute__((ext_vector_type(2)));
typedef float f32x4 __attribute__((ext_vector_type(4)));
typedef int int4v __attribute__((ext_vector_type(4)));
typedef int int2v __attribute__((ext_vector_type(2)));

#define DEV static __device__ __forceinline__

DEV void gload16(const void* g, void* l) {
    __builtin_amdgcn_global_load_lds(
        (const __attribute__((address_space(1))) void*)g,
        (__attribute__((address_space(3))) void*)l, 16, 0, 0);
}

DEV f32x4 mfma16(bf16x8 a, bf16x8 b, f32x4 c) {
    return __builtin_amdgcn_mfma_f32_16x16x32_bf16(a, b, c, 0, 0, 0);
}

DEV int cvtpk(float lo, float hi) {
    int r;
    asm("v_cvt_pk_bf16_f32 %0, %1, %2" : "=v"(r) : "v"(lo), "v"(hi));
    return r;
}

DEV float rexp2(float x) {   // raw v_exp_f32 (no denormal guard)
    float r;
    asm("v_exp_f32 %0, %1" : "=v"(r) : "v"(x));
    return r;
}

// ---------------------------------------------------------------
// Fused first-stage: blocks 0..255 = transpose+LN1 (h = LN(x^T));
// blocks 256..3327 = the 4 weight transposes (fp32 [K][N] -> bf16 [N][K]).
__global__ __launch_bounds__(512, 2)
void k_pre(const float* __restrict__ x, const float* __restrict__ gg,
           const float* __restrict__ bb, bf16* __restrict__ h,
           const float* __restrict__ w0, const float* __restrict__ w1,
           const float* __restrict__ w2, const float* __restrict__ w3,
           bf16* __restrict__ d0, bf16* __restrict__ d1,
           bf16* __restrict__ d2, bf16* __restrict__ d3) {
    __shared__ char sm[35840];
    int bid = blockIdx.x;
    int t = threadIdx.x;

    if (bid >= 256) {
        float* tile = (float*)sm;              // [32][33]
        int tt = bid - 256;
        const float* w;
        bf16* d;
        int K, N, ti;
        if (tt < 768)       { w = w0; d = d0; K = 512;  N = 1536; ti = tt; }
        else if (tt < 1024) { w = w1; d = d1; K = 512;  N = 512;  ti = tt - 768; }
        else if (tt < 2048) { w = w2; d = d2; K = 512;  N = 2048; ti = tt - 1024; }
        else                { w = w3; d = d3; K = 2048; N = 512;  ti = tt - 2048; }
        int ntn = N >> 5;
        int kt = ti / ntn, ntile = ti % ntn;
        int k0 = kt * 32, n0 = ntile * 32;
        int nl = t & 31, kl = t >> 5;
#pragma unroll
        for (int i = 0; i < 2; i++) {
            int k = kl + i * 16;
            tile[k * 33 + nl] = w[(size_t)(k0 + k) * N + n0 + nl];
        }
        __syncthreads();
        int kl2 = t & 31, nl2 = t >> 5;
#pragma unroll
        for (int i = 0; i < 2; i++) {
            int n = nl2 + i * 16;
            d[(size_t)(n0 + n) * K + k0 + kl2] = (bf16)tile[kl2 * 33 + n];
        }
        return;
    }

    bf16* big = (bf16*)sm;                     // [32][524]
    float* red = (float*)(sm + 33536);         // [8][32][2]
    float* mures = (float*)(sm + 35584);       // [32][2]
    int nt = bid & 127, b = bid >> 7;
    int n0 = nt * 32;

    int n = t & 31, cg = t >> 5;
    const float* xp = x + (size_t)b * 512 * 4096 +
                      (size_t)(cg * 32) * 4096 + n0 + n;
    float s = 0.f, ss = 0.f;
#pragma unroll
    for (int i = 0; i < 32; i++) {
        float v = xp[(size_t)i * 4096];
        s += v;
        ss += v * v;
        big[n * 524 + cg * 32 + i] = (bf16)v;
    }
    s += __shfl_xor(s, 32);
    ss += __shfl_xor(ss, 32);
    int w = t >> 6, l = t & 63;
    if (l < 32) {
        red[(w * 32 + n) * 2] = s;
        red[(w * 32 + n) * 2 + 1] = ss;
    }
    __syncthreads();
    if (t < 32) {
        float ts = 0.f, tss = 0.f;
#pragma unroll
        for (int ww = 0; ww < 8; ww++) {
            ts += red[(ww * 32 + t) * 2];
            tss += red[(ww * 32 + t) * 2 + 1];
        }
        float mu = ts * (1.f / 512.f);
        float var = tss * (1.f / 512.f) - mu * mu;
        mures[t * 2] = mu;
        mures[t * 2 + 1] = rsqrtf(var + 1e-5f);
    }
    __syncthreads();

    int nw = t >> 4, cs = t & 15;
    float mu = mures[nw * 2], rs = mures[nw * 2 + 1];
    bf16* hd = h + (size_t)(b * 4096 + n0 + nw) * 512;
#pragma unroll
    for (int j = 0; j < 4; j++) {
        int c = cs * 8 + j * 128;
        bf16x8 vv = *(const bf16x8*)&big[nw * 524 + c];
        f32x4 g0v = *(const f32x4*)(gg + c);
        f32x4 g1v = *(const f32x4*)(gg + c + 4);
        f32x4 b0v = *(const f32x4*)(bb + c);
        f32x4 b1v = *(const f32x4*)(bb + c + 4);
        bf16x8 o;
#pragma unroll
        for (int k = 0; k < 4; k++) {
            o[k] = (bf16)(((float)vv[k] - mu) * rs * g0v[k] + b0v[k]);
            o[k + 4] = (bf16)(((float)vv[k + 4] - mu) * rs * g1v[k] + b1v[k]);
        }
        *(bf16x8*)(hd + c) = o;
    }
}

// ---------------------------------------------------------------
// Fused residual + transpose + LayerNorm: h[n][c] = LN_c(x^T + po).
__global__ __launch_bounds__(512, 2)
void k_tln2(const float* __restrict__ x, const bf16* __restrict__ po,
            const float* __restrict__ gg, const float* __restrict__ bb,
            bf16* __restrict__ h) {
    __shared__ char sm[69632];
    bf16* big = (bf16*)sm;                     // [32][524]
    float* red = (float*)(sm + 33536);         // [8][32][2]
    float* mures = (float*)(sm + 35584);       // [32][2]
    bf16* pob = (bf16*)(sm + 35840);           // [32][524]

    int t = threadIdx.x;
    int bid = blockIdx.x;
    int nt = bid & 127, b = bid >> 7;
    int n0 = nt * 32;

    {
        int rr = t >> 4, cs16 = t & 15;
        const bf16* ps = po + (size_t)(b * 4096 + n0 + rr) * 512 + cs16 * 32;
#pragma unroll
        for (int j = 0; j < 4; j++)
            *(bf16x8*)&pob[rr * 524 + cs16 * 32 + j * 8] =
                *(const bf16x8*)(ps + j * 8);
        __syncthreads();
    }

    int n = t & 31, cg = t >> 5;
    const float* xp = x + (size_t)b * 512 * 4096 +
                      (size_t)(cg * 32) * 4096 + n0 + n;
    float s = 0.f, ss = 0.f;
#pragma unroll
    for (int i = 0; i < 32; i++) {
        float v = xp[(size_t)i * 4096] + (float)pob[n * 524 + cg * 32 + i];
        s += v;
        ss += v * v;
        big[n * 524 + cg * 32 + i] = (bf16)v;
    }
    s += __shfl_xor(s, 32);
    ss += __shfl_xor(ss, 32);
    int w = t >> 6, l = t & 63;
    if (l < 32) {
        red[(w * 32 + n) * 2] = s;
        red[(w * 32 + n) * 2 + 1] = ss;
    }
    __syncthreads();
    if (t < 32) {
        float ts = 0.f, tss = 0.f;
#pragma unroll
        for (int ww = 0; ww < 8; ww++) {
            ts += red[(ww * 32 + t) * 2];
            tss += red[(ww * 32 + t) * 2 + 1];
        }
        float mu = ts * (1.f / 512.f);
        float var = tss * (1.f / 512.f) - mu * mu;
        mures[t * 2] = mu;
        mures[t * 2 + 1] = rsqrtf(var + 1e-5f);
    }
    __syncthreads();

    int nw = t >> 4, cs = t & 15;
    float mu = mures[nw * 2], rs = mures[nw * 2 + 1];
    bf16* hd = h + (size_t)(b * 4096 + n0 + nw) * 512;
#pragma unroll
    for (int j = 0; j < 4; j++) {
        int c = cs * 8 + j * 128;
        bf16x8 vv = *(const bf16x8*)&big[nw * 524 + c];
        f32x4 g0v = *(const f32x4*)(gg + c);
        f32x4 g1v = *(const f32x4*)(gg + c + 4);
        f32x4 b0v = *(const f32x4*)(bb + c);
        f32x4 b1v = *(const f32x4*)(bb + c + 4);
        bf16x8 o;
#pragma unroll
        for (int k = 0; k < 4; k++) {
            o[k] = (bf16)(((float)vv[k] - mu) * rs * g0v[k] + b0v[k]);
            o[k + 4] = (bf16)(((float)vv[k + 4] - mu) * rs * g1v[k] + b1v[k]);
        }
        *(bf16x8*)(hd + c) = o;
    }
}

// ---------------------------------------------------------------
// GEMM (2-phase): out[M][N](bf16) = A @ BT^T + bias.
// MODE 0 plain / 2 qkv (V-slice transposed into vt) / 3 ffn2+final.
template <int MODE, int BN>
__global__ __launch_bounds__(256, BN == 64 ? 3 : 2)
void k_gemm(const bf16* __restrict__ A, const bf16* __restrict__ BT,
            const float* __restrict__ bias, bf16* __restrict__ outb,
            bf16* __restrict__ vtout, const float* __restrict__ xin,
            const bf16* __restrict__ poin, float* __restrict__ yout,
            int M, int N, int K) {
    constexpr int CG = BN / 32;
    constexpr int BSZ = CG * 4096;
    __shared__ char smem[32768 + 2 * BSZ];
    int ntn = N / BN;
    int nwg = gridDim.x;
    int bid = blockIdx.x;
    int cpx = nwg >> 3;
    bid = (bid & 7) * cpx + (bid >> 3);       // XCD-aware swizzle
    int bm = bid / ntn, bn = bid % ntn;
    int m0 = bm * 128, n0 = bn * BN;
    int tid = threadIdx.x;
    int w = tid >> 6, l = tid & 63;
    int wm = w >> 1, wn = w & 1;
    int l15 = l & 15, lg = l >> 4;

    f32x4 acc[4][CG];
#pragma unroll
    for (int i = 0; i < 4; i++)
#pragma unroll
        for (int j = 0; j < CG; j++) acc[i][j] = (f32x4){0.f, 0.f, 0.f, 0.f};

    int srow = tid >> 3, sphys = tid & 7;
    int lrow_a = wm * 64 + l15;
    int lrow_b = wn * (BN / 2) + l15;

#define GEMM_STAGE(k0v, bb)                                                  \
    do {                                                                     \
        _Pragma("unroll") for (int s = 0; s < 4; s++) {                      \
            int row = s * 32 + srow;                                         \
            int k16 = sphys ^ (row & 7);                                     \
            gload16(A + (size_t)(m0 + row) * K + (k0v) + k16 * 8,            \
                    smem + (bb) * 16384 + s * 4096 + tid * 16);              \
        }                                                                    \
        _Pragma("unroll") for (int s = 0; s < CG; s++) {                     \
            int row = s * 32 + srow;                                         \
            int k16 = sphys ^ (row & 7);                                     \
            gload16(BT + (size_t)(n0 + row) * K + (k0v) + k16 * 8,           \
                    smem + 32768 + (bb) * BSZ + s * 4096 + tid * 16);        \
        }                                                                    \
    } while (0)

    int nk = K >> 6;
    GEMM_STAGE(0, 0);
    int cur = 0;
    for (int kt = 0; kt < nk; kt++) {
        if (kt + 1 < nk) {
            GEMM_STAGE((kt + 1) << 6, cur ^ 1);
            if constexpr (BN == 128)
                asm volatile("s_waitcnt vmcnt(8)" ::: "memory");
            else
                asm volatile("s_waitcnt vmcnt(6)" ::: "memory");
        } else {
            asm volatile("s_waitcnt vmcnt(0)" ::: "memory");
        }
        __builtin_amdgcn_s_barrier();
        __builtin_amdgcn_sched_barrier(0);
        const char* pA = smem + cur * 16384;
        const char* pB = smem + 32768 + cur * BSZ;
#pragma unroll
        for (int ks = 0; ks < 2; ks++) {
            bf16x8 af[4], bfr[CG];
#pragma unroll
            for (int rg = 0; rg < 4; rg++) {
                int row = lrow_a + rg * 16;
                af[rg] = *(const bf16x8*)(pA + row * 128 +
                                          (((lg + ks * 4) ^ (row & 7)) << 4));
            }
#pragma unroll
            for (int cg = 0; cg < CG; cg++) {
                int row = lrow_b + cg * 16;
                bfr[cg] = *(const bf16x8*)(pB + row * 128 +
                                           (((lg + ks * 4) ^ (row & 7)) << 4));
            }
#pragma unroll
            for (int rg = 0; rg < 4; rg++)
#pragma unroll
                for (int cg = 0; cg < CG; cg++)
                    acc[rg][cg] = mfma16(af[rg], bfr[cg], acc[rg][cg]);
        }
        __builtin_amdgcn_s_barrier();
        cur ^= 1;
    }
#undef GEMM_STAGE

    if constexpr (MODE == 2) {
        if (n0 >= 1024) {
            char* vl = smem;        // col-major [BN col][136 row] bf16
#pragma unroll
            for (int cg = 0; cg < CG; cg++) {
                int col = wn * (BN / 2) + cg * 16 + l15;
                float bz = bias[n0 + col];
#pragma unroll
                for (int rg = 0; rg < 4; rg++) {
                    int rowb = wm * 64 + rg * 16 + lg * 4;
                    int2v qq = {cvtpk(acc[rg][cg][0] + bz, acc[rg][cg][1] + bz),
                                cvtpk(acc[rg][cg][2] + bz, acc[rg][cg][3] + bz)};
                    *(int2v*)(vl + col * 272 + rowb * 2) = qq;
                }
            }
            __syncthreads();
            int b = m0 >> 12, nrow0 = m0 & 4095;
            int dl = tid >> 3, c8 = tid & 7;
#pragma unroll
            for (int dd = 0; dd < BN / 32; dd++) {
                int d = dd * 32 + dl;
                int ch = (n0 - 1024) + d;
                bf16* dst = vtout +
                    ((size_t)((b * 8 + (ch >> 6)) * 64 + (ch & 63))) * 4096 + nrow0;
#pragma unroll
                for (int half = 0; half < 2; half++) {
                    int chunk = half * 8 + c8;
                    bf16x8 vv = *(const bf16x8*)(vl + d * 272 + chunk * 16);
                    *(bf16x8*)(dst + chunk * 8) = vv;
                }
            }
            return;
        }
    }

    if constexpr (MODE == 3) {
        // ---- fused final: y[b][c][n] = 2x + po + (acc + bias)
        float* ts = (float*)smem;            // [64 c][132 n] fp32
        int b = m0 >> 12, nrow0 = m0 & 4095;
#pragma unroll
        for (int cg = 0; cg < CG; cg++) {
            int lcol = wn * (BN / 2) + cg * 16 + l15;
            float bz = bias[n0 + lcol];
#pragma unroll
            for (int rg = 0; rg < 4; rg++) {
#pragma unroll
                for (int j = 0; j < 4; j++) {
                    int lrow = wm * 64 + rg * 16 + lg * 4 + j;
                    float v = acc[rg][cg][j] + bz +
                        (float)poin[(size_t)(m0 + lrow) * 512 + n0 + lcol];
                    ts[lcol * 132 + lrow] = v;
                }
            }
        }
        __syncthreads();
        int nl = (tid & 31) * 4, chh = tid >> 5;
#pragma unroll
        for (int q = 0; q < 8; q++) {
            int c = chh + q * 8;
            size_t off = ((size_t)b * 512 + n0 + c) * 4096 + nrow0 + nl;
            f32x4 xv = *(const f32x4*)(xin + off);
            f32x4 tv = *(const f32x4*)&ts[c * 132 + nl];
            f32x4 ov;
#pragma unroll
            for (int k2 = 0; k2 < 4; k2++) ov[k2] = 2.f * xv[k2] + tv[k2];
            *(f32x4*)(yout + off) = ov;
        }
        return;
    }

    constexpr int RS = BN * 2 + 8;
    constexpr int CH = BN / 8;
    char* ep = smem;
#pragma unroll
    for (int cg = 0; cg < CG; cg++) {
        int lcol = wn * (BN / 2) + cg * 16 + l15;
        float bz = bias[n0 + lcol];
#pragma unroll
        for (int rg = 0; rg < 4; rg++) {
#pragma unroll
            for (int j = 0; j < 4; j++) {
                int lrow = wm * 64 + rg * 16 + lg * 4 + j;
                float v = acc[rg][cg][j] + bz;
                *(bf16*)(ep + lrow * RS + lcol * 2) = (bf16)v;
            }
        }
    }
    __syncthreads();
    int cch = tid & (CH - 1);
    int rof = tid / CH;
    constexpr int RPP = 256 / CH;
#pragma unroll
    for (int i = 0; i < 128 / RPP; i++) {
        int row = i * RPP + rof;
        bf16x8 vv = *(const bf16x8*)(ep + row * RS + cch * 16);
        *(bf16x8*)(outb + (size_t)(m0 + row) * N + n0 + cch * 8) = vv;
    }
}

// ---------------------------------------------------------------
// FFN1 GEMM, 8-phase 256^2 schedule (T3+T4): M=8192 N=2048 K=512, relu.
__global__ __launch_bounds__(512, 2)
void k_gemm8(const bf16* __restrict__ A, const bf16* __restrict__ BT,
             const float* __restrict__ bias, bf16* __restrict__ outb) {
    __shared__ char sL[131072];   // A: [2buf][2s][256r][64B] @0; B same @65536
    int bid = blockIdx.x;
    bid = (bid & 7) * 32 + (bid >> 3);        // XCD swizzle (grid 256)
    int bm = bid >> 3, bn = bid & 7;
    int m0 = bm * 256, n0 = bn * 256;
    int tid = threadIdx.x;
    int w = tid >> 6, l = tid & 63;
    int wm = w >> 2, wn = w & 3;              // 2M x 4N waves
    int l15 = l & 15, lg = l >> 4;
    int cpr = (lg ^ ((l15 >> 1) & 3)) << 4;   // read chunk byte-offset (lane-inv)

    f32x4 acc[8][4];
#pragma unroll
    for (int i = 0; i < 8; i++)
#pragma unroll
        for (int j = 0; j < 4; j++) acc[i][j] = (f32x4){0.f, 0.f, 0.f, 0.f};

    int srow = tid >> 2, scp = tid & 3;
    int kofs = (scp ^ ((srow >> 1) & 3)) * 8;
    const bf16* gA0 = A + (size_t)(m0 + srow) * 512 + kofs;
    const bf16* gA1 = gA0 + 128 * 512;
    const bf16* gB0 = BT + (size_t)(n0 + srow) * 512 + kofs;
    const bf16* gB1 = gB0 + 128 * 512;
    char* dA = sL + tid * 16;
    char* dB = sL + 65536 + tid * 16;
    const char* pA0 = sL + (wm * 128 + l15) * 64 + cpr;
    const char* pB0 = sL + 65536 + (wn * 64 + l15) * 64 + cpr;

#define STGA(T, S, BUF)                                                       \
    gload16(gA0 + (T) * 64 + (S) * 32, dA + (BUF) * 32768 + (S) * 16384);     \
    gload16(gA1 + (T) * 64 + (S) * 32, dA + (BUF) * 32768 + (S) * 16384 + 8192);
#define STGB(T, S, BUF)                                                       \
    gload16(gB0 + (T) * 64 + (S) * 32, dB + (BUF) * 32768 + (S) * 16384);     \
    gload16(gB1 + (T) * 64 + (S) * 32, dB + (BUF) * 32768 + (S) * 16384 + 8192);
#define WB8 asm volatile("s_waitcnt vmcnt(8)" ::: "memory"); __builtin_amdgcn_s_barrier();
#define WB4 asm volatile("s_waitcnt vmcnt(4)" ::: "memory"); __builtin_amdgcn_s_barrier();
#define WB0 asm volatile("s_waitcnt vmcnt(0)" ::: "memory"); __builtin_amdgcn_s_barrier();
#define WBN

    bf16x8 bfr[4];

#define PH(BUF, S, RGH, WAITC, STGC)                                          \
    {                                                                         \
        WAITC                                                                 \
        if ((RGH) == 0) {                                                     \
            _Pragma("unroll") for (int cg = 0; cg < 4; cg++)                  \
                bfr[cg] = *(const bf16x8*)(pB0 + (BUF) * 32768 +              \
                                           (S) * 16384 + cg * 1024);          \
        }                                                                     \
        bf16x8 af[4];                                                         \
        _Pragma("unroll") for (int i = 0; i < 4; i++)                         \
            af[i] = *(const bf16x8*)(pA0 + (BUF) * 32768 + (S) * 16384 +      \
                                     ((RGH) * 4 + i) * 1024);                 \
        STGC                                                                  \
        __builtin_amdgcn_s_barrier();                                         \
        asm volatile("s_waitcnt lgkmcnt(0)" ::: "memory");                    \
        __builtin_amdgcn_sched_barrier(0);                                    \
        __builtin_amdgcn_s_setprio(1);                                        \
        _Pragma("unroll") for (int i = 0; i < 4; i++)                         \
            _Pragma("unroll") for (int cg = 0; cg < 4; cg++)                  \
                acc[(RGH) * 4 + i][cg] =                                      \
                    mfma16(af[i], bfr[cg], acc[(RGH) * 4 + i][cg]);           \
        __builtin_amdgcn_s_setprio(0);                                        \
    }

#define TILEF(T, BUF)                                                         \
    PH(BUF, 0, 0, WB8, STGA(T + 1, 1, BUF ^ 1))                               \
    PH(BUF, 0, 1, WBN, STGB(T + 1, 1, BUF ^ 1))                               \
    PH(BUF, 1, 0, WB8, STGA(T + 2, 0, BUF))                                   \
    PH(BUF, 1, 1, WBN, STGB(T + 2, 0, BUF))

    STGA(0, 0, 0) STGB(0, 0, 0) STGA(0, 1, 0) STGB(0, 1, 0)
    STGA(1, 0, 1) STGB(1, 0, 1)

    TILEF(0, 0) TILEF(1, 1) TILEF(2, 0) TILEF(3, 1) TILEF(4, 0) TILEF(5, 1)
    PH(0, 0, 0, WB8, STGA(7, 1, 1))
    PH(0, 0, 1, WBN, STGB(7, 1, 1))
    PH(0, 1, 0, WB8, )
    PH(0, 1, 1, WBN, )
    PH(1, 0, 0, WB4, )
    PH(1, 0, 1, WBN, )
    PH(1, 1, 0, WB0, )
    PH(1, 1, 1, WBN, )
#undef TILEF
#undef PH
#undef WB8
#undef WB4
#undef WB0
#undef WBN
#undef STGA
#undef STGB

    // epilogue: relu + 2-pass LDS bounce (rows 0-127, 128-255)
    float bz[4];
#pragma unroll
    for (int cg = 0; cg < 4; cg++) bz[cg] = bias[n0 + wn * 64 + cg * 16 + l15];
#pragma unroll
    for (int h2 = 0; h2 < 2; h2++) {
        __syncthreads();
        if (wm == h2) {
#pragma unroll
            for (int rg = 0; rg < 8; rg++)
#pragma unroll
                for (int cg = 0; cg < 4; cg++)
#pragma unroll
                    for (int j = 0; j < 4; j++) {
                        int rl = rg * 16 + lg * 4 + j;
                        int cl = wn * 64 + cg * 16 + l15;
                        float v = fmaxf(acc[rg][cg][j] + bz[cg], 0.f);
                        *(bf16*)(sL + rl * 520 + cl * 2) = (bf16)v;
                    }
        }
        __syncthreads();
        int cch = tid & 31, rof = tid >> 5;
#pragma unroll
        for (int p = 0; p < 8; p++) {
            int row = p * 16 + rof;
            bf16x8 vv = *(const bf16x8*)(sL + row * 520 + cch * 16);
            *(bf16x8*)(outb + (size_t)(m0 + h2 * 128 + row) * 2048 +
                       n0 + cch * 8) = vv;
        }
    }
}

// ---------------------------------------------------------------
// Flash attention v11 (verified best): 8 waves / 128 q-rows per block,
// 2-buf dbuf, counted vmcnt, intra-phase QK/exp/PV interleave, no online
// max, lsum via ones-MFMA.
__global__ __launch_bounds__(512, 4)
void k_attn(const bf16* __restrict__ qkvb, const bf16* __restrict__ vt,
            bf16* __restrict__ attno) {
    __shared__ bf16 sK[2][64 * 64];
    __shared__ bf16 sV[2][64 * 64];
    const float sc = 0.044194173824159216f * 1.4426950408889634f; // 1/sqrt(512)*log2e
    int bid = blockIdx.x;
    int nb = (bid & 7) * 64 + (bid >> 3);     // XCD swizzle: 2 bh per XCD
    int bh = nb >> 5, qt = nb & 31;
    int b = bh >> 3, hh = bh & 7;
    int q0 = qt * 128;
    int tid = threadIdx.x, w = tid >> 6, l = tid & 63;
    int l15 = l & 15, lg = l >> 4, l7 = l15 & 7;
    int vperm = ((lg & 1) << 1) | (lg >> 1);
    const bf16* qbase = qkvb + (size_t)b * 4096 * 1536 + hh * 64;
    const bf16* kbase = qbase + 512;
    const bf16* vbase = vt + (size_t)bh * 64 * 4096;
    int srow = tid >> 3, sphys = tid & 7;     // srow 0..63: full 64-row tile

    const char* kp0 = (const char*)&sK[0][0] + l15 * 128 + ((lg ^ l7) << 4);
    const char* kp1 = (const char*)&sK[0][0] + l15 * 128 + (((4 + lg) ^ l7) << 4);
    const char* vp0 = (const char*)&sV[0][0] + l15 * 128 + ((vperm ^ l7) << 4);
    const char* vp1 = (const char*)&sV[0][0] + l15 * 128 + (((4 + vperm) ^ l7) << 4);
    char* dK0 = (char*)&sK[0][0] + tid * 16;  // 512 thr x 16B = full 8KB buf
    char* dV0 = (char*)&sV[0][0] + tid * 16;
    const char* kg = (const char*)(kbase + srow * 1536 + (sphys ^ (srow & 7)) * 8);
    const char* vg = (const char*)(vbase + srow * 4096 + (sphys ^ (srow & 7)) * 8);

    gload16(kg, dK0);
    gload16(vg, dV0);
    kg += 196608;
    vg += 128;

    bf16x8 qf[2];
#pragma unroll
    for (int ks = 0; ks < 2; ks++) {
        bf16x8 v = *(const bf16x8*)(qbase +
            (size_t)(q0 + w * 16 + l15) * 1536 + ks * 32 + lg * 8);
        bf16x8 o;
#pragma unroll
        for (int j = 0; j < 8; j++) o[j] = (bf16)((float)v[j] * sc);
        qf[ks] = o;
    }
    bf16x8 ones;
#pragma unroll
    for (int j = 0; j < 8; j++) ones[j] = (bf16)1.0f;

    const f32x4 kZ = {0.f, 0.f, 0.f, 0.f};
    f32x4 accl = kZ;
    f32x4 acc[4];
#pragma unroll
    for (int df = 0; df < 4; df++) acc[df] = kZ;

#define ABODY(BUF, PF)                                                        \
    {                                                                         \
        if (PF) {                                                             \
            gload16(kg, dK0 + (1 - (BUF)) * 8192);                            \
            gload16(vg, dV0 + (1 - (BUF)) * 8192);                            \
            kg += 196608;                                                     \
            vg += 128;                                                        \
            asm volatile("s_waitcnt vmcnt(2)" ::: "memory");                  \
        } else {                                                              \
            asm volatile("s_waitcnt vmcnt(0)" ::: "memory");                  \
        }                                                                     \
        __builtin_amdgcn_s_barrier();                                         \
        __builtin_amdgcn_sched_barrier(0);                                    \
        f32x4 s0, s1, s2, s3;                                                 \
        __builtin_amdgcn_s_setprio(1);                                        \
        s0 = mfma16(*(const bf16x8*)(kp0 + (BUF) * 8192 + 0 * 2048), qf[0], kZ); \
        s0 = mfma16(*(const bf16x8*)(kp1 + (BUF) * 8192 + 0 * 2048), qf[1], s0); \
        s1 = mfma16(*(const bf16x8*)(kp0 + (BUF) * 8192 + 1 * 2048), qf[0], kZ); \
        s1 = mfma16(*(const bf16x8*)(kp1 + (BUF) * 8192 + 1 * 2048), qf[1], s1); \
        __builtin_amdgcn_s_setprio(0);                                        \
        float e0 = rexp2(s0[0]), e1 = rexp2(s0[1]);                           \
        float e2 = rexp2(s0[2]), e3 = rexp2(s0[3]);                           \
        float e4 = rexp2(s1[0]), e5 = rexp2(s1[1]);                           \
        float e6 = rexp2(s1[2]), e7 = rexp2(s1[3]);                           \
        __builtin_amdgcn_s_setprio(1);                                        \
        s2 = mfma16(*(const bf16x8*)(kp0 + (BUF) * 8192 + 2 * 2048), qf[0], kZ); \
        s2 = mfma16(*(const bf16x8*)(kp1 + (BUF) * 8192 + 2 * 2048), qf[1], s2); \
        s3 = mfma16(*(const bf16x8*)(kp0 + (BUF) * 8192 + 3 * 2048), qf[0], kZ); \
        s3 = mfma16(*(const bf16x8*)(kp1 + (BUF) * 8192 + 3 * 2048), qf[1], s3); \
        __builtin_amdgcn_s_setprio(0);                                        \
        int p0 = cvtpk(e0, e1), p1 = cvtpk(e2, e3);                           \
        int p2 = cvtpk(e4, e5), p3 = cvtpk(e6, e7);                           \
        asm("v_permlane16_swap_b32 %0, %1" : "+v"(p2), "+v"(p0));             \
        asm("v_permlane16_swap_b32 %0, %1" : "+v"(p3), "+v"(p1));             \
        {                                                                     \
            int4v ai = {p0, p1, p2, p3};                                      \
            bf16x8 af = __builtin_bit_cast(bf16x8, ai);                       \
            __builtin_amdgcn_s_setprio(1);                                    \
            acc[0] = mfma16(af, *(const bf16x8*)(vp0 + (BUF) * 8192 + 0 * 2048), acc[0]); \
            acc[1] = mfma16(af, *(const bf16x8*)(vp0 + (BUF) * 8192 + 1 * 2048), acc[1]); \
            acc[2] = mfma16(af, *(const bf16x8*)(vp0 + (BUF) * 8192 + 2 * 2048), acc[2]); \
            acc[3] = mfma16(af, *(const bf16x8*)(vp0 + (BUF) * 8192 + 3 * 2048), acc[3]); \
            accl = mfma16(af, ones, accl);                                    \
            __builtin_amdgcn_s_setprio(0);                                    \
        }                                                                     \
        float e8 = rexp2(s2[0]), e9 = rexp2(s2[1]);                           \
        float e10 = rexp2(s2[2]), e11 = rexp2(s2[3]);                         \
        float e12 = rexp2(s3[0]), e13 = rexp2(s3[1]);                         \
        float e14 = rexp2(s3[2]), e15 = rexp2(s3[3]);                         \
        int p4 = cvtpk(e8, e9), p5 = cvtpk(e10, e11);                         \
        int p6 = cvtpk(e12, e13), p7 = cvtpk(e14, e15);                       \
        asm("v_permlane16_swap_b32 %0, %1" : "+v"(p6), "+v"(p4));             \
        asm("v_permlane16_swap_b32 %0, %1" : "+v"(p7), "+v"(p5));             \
        {                                                                     \
            int4v ai = {p4, p5, p6, p7};                                      \
            bf16x8 af = __builtin_bit_cast(bf16x8, ai);                       \
            __builtin_amdgcn_s_setprio(1);                                    \
            acc[0] = mfma16(af, *(const bf16x8*)(vp1 + (BUF) * 8192 + 0 * 2048), acc[0]); \
            acc[1] = mfma16(af, *(const bf16x8*)(vp1 + (BUF) * 8192 + 1 * 2048), acc[1]); \
            acc[2] = mfma16(af, *(const bf16x8*)(vp1 + (BUF) * 8192 + 2 * 2048), acc[2]); \
            acc[3] = mfma16(af, *(const bf16x8*)(vp1 + (BUF) * 8192 + 3 * 2048), acc[3]); \
            accl = mfma16(af, ones, accl);                                    \
            __builtin_amdgcn_s_setprio(0);                                    \
        }                                                                     \
        __builtin_amdgcn_s_barrier();                                         \
    }

    for (int tt = 0; tt < 31; tt++) {
        ABODY(0, 1)
        ABODY(1, 1)
    }
    ABODY(0, 1)
    ABODY(1, 0)
#undef ABODY

    float invq[4];
#pragma unroll
    for (int j = 0; j < 4; j++) invq[j] = 1.0f / accl[j];

    // 8 waves x 2KB exactly fill the 16KB sK region
    bf16* ow = (bf16*)&sK[0][0] + w * 16 * 64;
#pragma unroll
    for (int df = 0; df < 4; df++) {
        int chunk = df * 2 + (l15 >> 3);
        int within = l15 & 7;
#pragma unroll
        for (int j = 0; j < 4; j++) {
            int q = lg * 4 + j;
            *(bf16*)((char*)ow + q * 128 + ((chunk ^ (q & 7)) << 4) + within * 2) =
                (bf16)(acc[df][j] * invq[j]);
        }
    }
    __syncthreads();
    const char* owr = (const char*)ow;
#pragma unroll
    for (int half = 0; half < 2; half++) {
        int r = l >> 2, ch = (l & 3) + half * 4;
        bf16x8 vv = *(const bf16x8*)(owr + r * 128 + ((ch ^ (r & 7)) << 4));
        *(bf16x8*)(attno + (size_t)(b * 4096 + q0 + w * 16 + r) * 512 +
                   hh * 64 + ch * 8) = vv;
    }
}

// ---------------------------------------------------------------
extern "C" void kernel_launch(void* const* d_in, const int* in_sizes, int n_in,
                              void* d_out, int out_size, void* d_ws, size_t ws_size,
                              hipStream_t stream) {
    const float* x = (const float*)d_in[0];
    const float* ln1g = (const float*)d_in[1];
    const float* ln1b = (const float*)d_in[2];
    const float* wqkv = (const float*)d_in[3];
    const float* bqkv = (const float*)d_in[4];
    const float* wproj = (const float*)d_in[5];
    const float* bproj = (const float*)d_in[6];
    const float* ln2g = (const float*)d_in[7];
    const float* ln2b = (const float*)d_in[8];
    const float* wffn1 = (const float*)d_in[9];
    const float* bffn1 = (const float*)d_in[10];
    const float* wffn2 = (const float*)d_in[11];
    const float* bffn2 = (const float*)d_in[12];
    float* y = (float*)d_out;

    char* ws = (char*)d_ws;
    bf16* po   = (bf16*)(ws + 0);             // 8.4M, live to end
    bf16* h    = (bf16*)(ws + 16777216);      // h1 / attno / h2 (sequential)
    bf16* qkvb = (bf16*)(ws + 25165824);      // 24M
    bf16* vtb  = (bf16*)(ws + 50331648);      // 8M
    bf16* f1   = (bf16*)(ws + 25165824);      // alias qkv+vt (dead after attn)
    bf16* wqT  = (bf16*)(ws + 58720256);
    bf16* wpT  = (bf16*)(ws + 60293120);
    bf16* w1T  = (bf16*)(ws + 60817408);
    bf16* w2T  = (bf16*)(ws + 62914560);
    bf16* attno = h;

    k_pre<<<3328, 512, 0, stream>>>(x, ln1g, ln1b, h,
                                    wqkv, wproj, wffn1, wffn2,
                                    wqT, wpT, w1T, w2T);
    k_gemm<2, 128><<<768, 256, 0, stream>>>(h, wqT, bqkv, qkvb, vtb,
                                            nullptr, nullptr, nullptr,
                                            8192, 1536, 512);
    k_attn<<<512, 512, 0, stream>>>(qkvb, vtb, attno);
    k_gemm<0, 64><<<512, 256, 0, stream>>>(attno, wpT, bproj, po, nullptr,
                                           nullptr, nullptr, nullptr,
                                           8192, 512, 512);
    k_tln2<<<256, 512, 0, stream>>>(x, po, ln2g, ln2b, h);
    k_gemm8<<<256, 512, 0, stream>>>(h, w1T, bffn1, f1);
    k_gemm<3, 64><<<512, 256, 0, stream>>>(f1, w2T, bffn2, nullptr, nullptr,
                                           x, po, y, 8192, 512, 2048);
}

// Round 20
// 170.931 us; speedup vs baseline: 1.0531x; 1.0059x over previous
//
#include <hip/hip_runtime.h>
#include <hip/hip_bf16.h>

typedef __bf16 bf16;
typedef __bf16 bf16x8 __attribute__((ext_vector_type(8)));
typedef __bf16 bf16x4 __attribute__((ext_vector_type(4)));
typedef __bf16 bf16x2 __attribute__((ext_vector_type(2)));
typedef float f32x4 __attribute__((ext_vector_type(4)));
typedef int int4v __attribute__((ext_vector_type(4)));
typedef int int2v __attribute__((ext_vector_type(2)));

#define DEV static __device__ __forceinline__

DEV void gload16(const void* g, void* l) {
    __builtin_amdgcn_global_load_lds(
        (const __attribute__((address_space(1))) void*)g,
        (__attribute__((address_space(3))) void*)l, 16, 0, 0);
}

DEV f32x4 mfma16(bf16x8 a, bf16x8 b, f32x4 c) {
    return __builtin_amdgcn_mfma_f32_16x16x32_bf16(a, b, c, 0, 0, 0);
}

DEV int cvtpk(float lo, float hi) {
    int r;
    asm("v_cvt_pk_bf16_f32 %0, %1, %2" : "=v"(r) : "v"(lo), "v"(hi));
    return r;
}

DEV float rexp2(float x) {   // raw v_exp_f32 (no denormal guard)
    float r;
    asm("v_exp_f32 %0, %1" : "=v"(r) : "v"(x));
    return r;
}

// ---------------------------------------------------------------
// Fused first-stage: blocks 0..255 = transpose+LN1 (h = LN(x^T));
// blocks 256..3327 = the 4 weight transposes (fp32 [K][N] -> bf16 [N][K]).
__global__ __launch_bounds__(512, 2)
void k_pre(const float* __restrict__ x, const float* __restrict__ gg,
           const float* __restrict__ bb, bf16* __restrict__ h,
           const float* __restrict__ w0, const float* __restrict__ w1,
           const float* __restrict__ w2, const float* __restrict__ w3,
           bf16* __restrict__ d0, bf16* __restrict__ d1,
           bf16* __restrict__ d2, bf16* __restrict__ d3) {
    __shared__ char sm[35840];
    int bid = blockIdx.x;
    int t = threadIdx.x;

    if (bid >= 256) {
        float* tile = (float*)sm;              // [32][33]
        int tt = bid - 256;
        const float* w;
        bf16* d;
        int K, N, ti;
        if (tt < 768)       { w = w0; d = d0; K = 512;  N = 1536; ti = tt; }
        else if (tt < 1024) { w = w1; d = d1; K = 512;  N = 512;  ti = tt - 768; }
        else if (tt < 2048) { w = w2; d = d2; K = 512;  N = 2048; ti = tt - 1024; }
        else                { w = w3; d = d3; K = 2048; N = 512;  ti = tt - 2048; }
        int ntn = N >> 5;
        int kt = ti / ntn, ntile = ti % ntn;
        int k0 = kt * 32, n0 = ntile * 32;
        int nl = t & 31, kl = t >> 5;
#pragma unroll
        for (int i = 0; i < 2; i++) {
            int k = kl + i * 16;
            tile[k * 33 + nl] = w[(size_t)(k0 + k) * N + n0 + nl];
        }
        __syncthreads();
        int kl2 = t & 31, nl2 = t >> 5;
#pragma unroll
        for (int i = 0; i < 2; i++) {
            int n = nl2 + i * 16;
            d[(size_t)(n0 + n) * K + k0 + kl2] = (bf16)tile[kl2 * 33 + n];
        }
        return;
    }

    bf16* big = (bf16*)sm;                     // [32][524]
    float* red = (float*)(sm + 33536);         // [8][32][2]
    float* mures = (float*)(sm + 35584);       // [32][2]
    int nt = bid & 127, b = bid >> 7;
    int n0 = nt * 32;

    int n = t & 31, cg = t >> 5;
    const float* xp = x + (size_t)b * 512 * 4096 +
                      (size_t)(cg * 32) * 4096 + n0 + n;
    float s = 0.f, ss = 0.f;
#pragma unroll
    for (int i = 0; i < 32; i++) {
        float v = xp[(size_t)i * 4096];
        s += v;
        ss += v * v;
        big[n * 524 + cg * 32 + i] = (bf16)v;
    }
    s += __shfl_xor(s, 32);
    ss += __shfl_xor(ss, 32);
    int w = t >> 6, l = t & 63;
    if (l < 32) {
        red[(w * 32 + n) * 2] = s;
        red[(w * 32 + n) * 2 + 1] = ss;
    }
    __syncthreads();
    if (t < 32) {
        float ts = 0.f, tss = 0.f;
#pragma unroll
        for (int ww = 0; ww < 8; ww++) {
            ts += red[(ww * 32 + t) * 2];
            tss += red[(ww * 32 + t) * 2 + 1];
        }
        float mu = ts * (1.f / 512.f);
        float var = tss * (1.f / 512.f) - mu * mu;
        mures[t * 2] = mu;
        mures[t * 2 + 1] = rsqrtf(var + 1e-5f);
    }
    __syncthreads();

    int nw = t >> 4, cs = t & 15;
    float mu = mures[nw * 2], rs = mures[nw * 2 + 1];
    bf16* hd = h + (size_t)(b * 4096 + n0 + nw) * 512;
#pragma unroll
    for (int j = 0; j < 4; j++) {
        int c = cs * 8 + j * 128;
        bf16x8 vv = *(const bf16x8*)&big[nw * 524 + c];
        f32x4 g0v = *(const f32x4*)(gg + c);
        f32x4 g1v = *(const f32x4*)(gg + c + 4);
        f32x4 b0v = *(const f32x4*)(bb + c);
        f32x4 b1v = *(const f32x4*)(bb + c + 4);
        bf16x8 o;
#pragma unroll
        for (int k = 0; k < 4; k++) {
            o[k] = (bf16)(((float)vv[k] - mu) * rs * g0v[k] + b0v[k]);
            o[k + 4] = (bf16)(((float)vv[k + 4] - mu) * rs * g1v[k] + b1v[k]);
        }
        *(bf16x8*)(hd + c) = o;
    }
}

// ---------------------------------------------------------------
// Fused residual + transpose + LayerNorm: h[n][c] = LN_c(x^T + po).
__global__ __launch_bounds__(512, 2)
void k_tln2(const float* __restrict__ x, const bf16* __restrict__ po,
            const float* __restrict__ gg, const float* __restrict__ bb,
            bf16* __restrict__ h) {
    __shared__ char sm[69632];
    bf16* big = (bf16*)sm;                     // [32][524]
    float* red = (float*)(sm + 33536);         // [8][32][2]
    float* mures = (float*)(sm + 35584);       // [32][2]
    bf16* pob = (bf16*)(sm + 35840);           // [32][524]

    int t = threadIdx.x;
    int bid = blockIdx.x;
    int nt = bid & 127, b = bid >> 7;
    int n0 = nt * 32;

    {
        int rr = t >> 4, cs16 = t & 15;
        const bf16* ps = po + (size_t)(b * 4096 + n0 + rr) * 512 + cs16 * 32;
#pragma unroll
        for (int j = 0; j < 4; j++)
            *(bf16x8*)&pob[rr * 524 + cs16 * 32 + j * 8] =
                *(const bf16x8*)(ps + j * 8);
        __syncthreads();
    }

    int n = t & 31, cg = t >> 5;
    const float* xp = x + (size_t)b * 512 * 4096 +
                      (size_t)(cg * 32) * 4096 + n0 + n;
    float s = 0.f, ss = 0.f;
#pragma unroll
    for (int i = 0; i < 32; i++) {
        float v = xp[(size_t)i * 4096] + (float)pob[n * 524 + cg * 32 + i];
        s += v;
        ss += v * v;
        big[n * 524 + cg * 32 + i] = (bf16)v;
    }
    s += __shfl_xor(s, 32);
    ss += __shfl_xor(ss, 32);
    int w = t >> 6, l = t & 63;
    if (l < 32) {
        red[(w * 32 + n) * 2] = s;
        red[(w * 32 + n) * 2 + 1] = ss;
    }
    __syncthreads();
    if (t < 32) {
        float ts = 0.f, tss = 0.f;
#pragma unroll
        for (int ww = 0; ww < 8; ww++) {
            ts += red[(ww * 32 + t) * 2];
            tss += red[(ww * 32 + t) * 2 + 1];
        }
        float mu = ts * (1.f / 512.f);
        float var = tss * (1.f / 512.f) - mu * mu;
        mures[t * 2] = mu;
        mures[t * 2 + 1] = rsqrtf(var + 1e-5f);
    }
    __syncthreads();

    int nw = t >> 4, cs = t & 15;
    float mu = mures[nw * 2], rs = mures[nw * 2 + 1];
    bf16* hd = h + (size_t)(b * 4096 + n0 + nw) * 512;
#pragma unroll
    for (int j = 0; j < 4; j++) {
        int c = cs * 8 + j * 128;
        bf16x8 vv = *(const bf16x8*)&big[nw * 524 + c];
        f32x4 g0v = *(const f32x4*)(gg + c);
        f32x4 g1v = *(const f32x4*)(gg + c + 4);
        f32x4 b0v = *(const f32x4*)(bb + c);
        f32x4 b1v = *(const f32x4*)(bb + c + 4);
        bf16x8 o;
#pragma unroll
        for (int k = 0; k < 4; k++) {
            o[k] = (bf16)(((float)vv[k] - mu) * rs * g0v[k] + b0v[k]);
            o[k + 4] = (bf16)(((float)vv[k + 4] - mu) * rs * g1v[k] + b1v[k]);
        }
        *(bf16x8*)(hd + c) = o;
    }
}

// ---------------------------------------------------------------
// GEMM (2-phase): out[M][N](bf16) = A @ BT^T + bias.
// MODE 0 plain / 2 qkv (V-slice transposed into vt) / 3 ffn2+final.
template <int MODE, int BN>
__global__ __launch_bounds__(256, BN == 64 ? 3 : 2)
void k_gemm(const bf16* __restrict__ A, const bf16* __restrict__ BT,
            const float* __restrict__ bias, bf16* __restrict__ outb,
            bf16* __restrict__ vtout, const float* __restrict__ xin,
            const bf16* __restrict__ poin, float* __restrict__ yout,
            int M, int N, int K) {
    constexpr int CG = BN / 32;
    constexpr int BSZ = CG * 4096;
    __shared__ char smem[32768 + 2 * BSZ];
    int ntn = N / BN;
    int nwg = gridDim.x;
    int bid = blockIdx.x;
    int cpx = nwg >> 3;
    bid = (bid & 7) * cpx + (bid >> 3);       // XCD-aware swizzle
    int bm = bid / ntn, bn = bid % ntn;
    int m0 = bm * 128, n0 = bn * BN;
    int tid = threadIdx.x;
    int w = tid >> 6, l = tid & 63;
    int wm = w >> 1, wn = w & 1;
    int l15 = l & 15, lg = l >> 4;

    f32x4 acc[4][CG];
#pragma unroll
    for (int i = 0; i < 4; i++)
#pragma unroll
        for (int j = 0; j < CG; j++) acc[i][j] = (f32x4){0.f, 0.f, 0.f, 0.f};

    int srow = tid >> 3, sphys = tid & 7;
    int lrow_a = wm * 64 + l15;
    int lrow_b = wn * (BN / 2) + l15;

#define GEMM_STAGE(k0v, bb)                                                  \
    do {                                                                     \
        _Pragma("unroll") for (int s = 0; s < 4; s++) {                      \
            int row = s * 32 + srow;                                         \
            int k16 = sphys ^ (row & 7);                                     \
            gload16(A + (size_t)(m0 + row) * K + (k0v) + k16 * 8,            \
                    smem + (bb) * 16384 + s * 4096 + tid * 16);              \
        }                                                                    \
        _Pragma("unroll") for (int s = 0; s < CG; s++) {                     \
            int row = s * 32 + srow;                                         \
            int k16 = sphys ^ (row & 7);                                     \
            gload16(BT + (size_t)(n0 + row) * K + (k0v) + k16 * 8,           \
                    smem + 32768 + (bb) * BSZ + s * 4096 + tid * 16);        \
        }                                                                    \
    } while (0)

    int nk = K >> 6;
    GEMM_STAGE(0, 0);
    int cur = 0;
    for (int kt = 0; kt < nk; kt++) {
        if (kt + 1 < nk) {
            GEMM_STAGE((kt + 1) << 6, cur ^ 1);
            if constexpr (BN == 128)
                asm volatile("s_waitcnt vmcnt(8)" ::: "memory");
            else
                asm volatile("s_waitcnt vmcnt(6)" ::: "memory");
        } else {
            asm volatile("s_waitcnt vmcnt(0)" ::: "memory");
        }
        __builtin_amdgcn_s_barrier();
        __builtin_amdgcn_sched_barrier(0);
        const char* pA = smem + cur * 16384;
        const char* pB = smem + 32768 + cur * BSZ;
#pragma unroll
        for (int ks = 0; ks < 2; ks++) {
            bf16x8 af[4], bfr[CG];
#pragma unroll
            for (int rg = 0; rg < 4; rg++) {
                int row = lrow_a + rg * 16;
                af[rg] = *(const bf16x8*)(pA + row * 128 +
                                          (((lg + ks * 4) ^ (row & 7)) << 4));
            }
#pragma unroll
            for (int cg = 0; cg < CG; cg++) {
                int row = lrow_b + cg * 16;
                bfr[cg] = *(const bf16x8*)(pB + row * 128 +
                                           (((lg + ks * 4) ^ (row & 7)) << 4));
            }
#pragma unroll
            for (int rg = 0; rg < 4; rg++)
#pragma unroll
                for (int cg = 0; cg < CG; cg++)
                    acc[rg][cg] = mfma16(af[rg], bfr[cg], acc[rg][cg]);
        }
        __builtin_amdgcn_s_barrier();
        cur ^= 1;
    }
#undef GEMM_STAGE

    if constexpr (MODE == 2) {
        if (n0 >= 1024) {
            char* vl = smem;        // col-major [BN col][136 row] bf16
#pragma unroll
            for (int cg = 0; cg < CG; cg++) {
                int col = wn * (BN / 2) + cg * 16 + l15;
                float bz = bias[n0 + col];
#pragma unroll
                for (int rg = 0; rg < 4; rg++) {
                    int rowb = wm * 64 + rg * 16 + lg * 4;
                    int2v qq = {cvtpk(acc[rg][cg][0] + bz, acc[rg][cg][1] + bz),
                                cvtpk(acc[rg][cg][2] + bz, acc[rg][cg][3] + bz)};
                    *(int2v*)(vl + col * 272 + rowb * 2) = qq;
                }
            }
            __syncthreads();
            int b = m0 >> 12, nrow0 = m0 & 4095;
            int dl = tid >> 3, c8 = tid & 7;
#pragma unroll
            for (int dd = 0; dd < BN / 32; dd++) {
                int d = dd * 32 + dl;
                int ch = (n0 - 1024) + d;
                bf16* dst = vtout +
                    ((size_t)((b * 8 + (ch >> 6)) * 64 + (ch & 63))) * 4096 + nrow0;
#pragma unroll
                for (int half = 0; half < 2; half++) {
                    int chunk = half * 8 + c8;
                    bf16x8 vv = *(const bf16x8*)(vl + d * 272 + chunk * 16);
                    *(bf16x8*)(dst + chunk * 8) = vv;
                }
            }
            return;
        }
    }

    if constexpr (MODE == 3) {
        // ---- fused final: y[b][c][n] = 2x + po + (acc + bias)
        float* ts = (float*)smem;            // [64 c][132 n] fp32
        int b = m0 >> 12, nrow0 = m0 & 4095;
#pragma unroll
        for (int cg = 0; cg < CG; cg++) {
            int lcol = wn * (BN / 2) + cg * 16 + l15;
            float bz = bias[n0 + lcol];
#pragma unroll
            for (int rg = 0; rg < 4; rg++) {
#pragma unroll
                for (int j = 0; j < 4; j++) {
                    int lrow = wm * 64 + rg * 16 + lg * 4 + j;
                    float v = acc[rg][cg][j] + bz +
                        (float)poin[(size_t)(m0 + lrow) * 512 + n0 + lcol];
                    ts[lcol * 132 + lrow] = v;
                }
            }
        }
        __syncthreads();
        int nl = (tid & 31) * 4, chh = tid >> 5;
#pragma unroll
        for (int q = 0; q < 8; q++) {
            int c = chh + q * 8;
            size_t off = ((size_t)b * 512 + n0 + c) * 4096 + nrow0 + nl;
            f32x4 xv = *(const f32x4*)(xin + off);
            f32x4 tv = *(const f32x4*)&ts[c * 132 + nl];
            f32x4 ov;
#pragma unroll
            for (int k2 = 0; k2 < 4; k2++) ov[k2] = 2.f * xv[k2] + tv[k2];
            *(f32x4*)(yout + off) = ov;
        }
        return;
    }

    constexpr int RS = BN * 2 + 8;
    constexpr int CH = BN / 8;
    char* ep = smem;
#pragma unroll
    for (int cg = 0; cg < CG; cg++) {
        int lcol = wn * (BN / 2) + cg * 16 + l15;
        float bz = bias[n0 + lcol];
#pragma unroll
        for (int rg = 0; rg < 4; rg++) {
#pragma unroll
            for (int j = 0; j < 4; j++) {
                int lrow = wm * 64 + rg * 16 + lg * 4 + j;
                float v = acc[rg][cg][j] + bz;
                *(bf16*)(ep + lrow * RS + lcol * 2) = (bf16)v;
            }
        }
    }
    __syncthreads();
    int cch = tid & (CH - 1);
    int rof = tid / CH;
    constexpr int RPP = 256 / CH;
#pragma unroll
    for (int i = 0; i < 128 / RPP; i++) {
        int row = i * RPP + rof;
        bf16x8 vv = *(const bf16x8*)(ep + row * RS + cch * 16);
        *(bf16x8*)(outb + (size_t)(m0 + row) * N + n0 + cch * 8) = vv;
    }
}

// ---------------------------------------------------------------
// FFN1 GEMM, 8-phase 256^2 schedule (T3+T4): M=8192 N=2048 K=512, relu.
__global__ __launch_bounds__(512, 2)
void k_gemm8(const bf16* __restrict__ A, const bf16* __restrict__ BT,
             const float* __restrict__ bias, bf16* __restrict__ outb) {
    __shared__ char sL[131072];   // A: [2buf][2s][256r][64B] @0; B same @65536
    int bid = blockIdx.x;
    bid = (bid & 7) * 32 + (bid >> 3);        // XCD swizzle (grid 256)
    int bm = bid >> 3, bn = bid & 7;
    int m0 = bm * 256, n0 = bn * 256;
    int tid = threadIdx.x;
    int w = tid >> 6, l = tid & 63;
    int wm = w >> 2, wn = w & 3;              // 2M x 4N waves
    int l15 = l & 15, lg = l >> 4;
    int cpr = (lg ^ ((l15 >> 1) & 3)) << 4;   // read chunk byte-offset (lane-inv)

    f32x4 acc[8][4];
#pragma unroll
    for (int i = 0; i < 8; i++)
#pragma unroll
        for (int j = 0; j < 4; j++) acc[i][j] = (f32x4){0.f, 0.f, 0.f, 0.f};

    int srow = tid >> 2, scp = tid & 3;
    int kofs = (scp ^ ((srow >> 1) & 3)) * 8;
    const bf16* gA0 = A + (size_t)(m0 + srow) * 512 + kofs;
    const bf16* gA1 = gA0 + 128 * 512;
    const bf16* gB0 = BT + (size_t)(n0 + srow) * 512 + kofs;
    const bf16* gB1 = gB0 + 128 * 512;
    char* dA = sL + tid * 16;
    char* dB = sL + 65536 + tid * 16;
    const char* pA0 = sL + (wm * 128 + l15) * 64 + cpr;
    const char* pB0 = sL + 65536 + (wn * 64 + l15) * 64 + cpr;

#define STGA(T, S, BUF)                                                       \
    gload16(gA0 + (T) * 64 + (S) * 32, dA + (BUF) * 32768 + (S) * 16384);     \
    gload16(gA1 + (T) * 64 + (S) * 32, dA + (BUF) * 32768 + (S) * 16384 + 8192);
#define STGB(T, S, BUF)                                                       \
    gload16(gB0 + (T) * 64 + (S) * 32, dB + (BUF) * 32768 + (S) * 16384);     \
    gload16(gB1 + (T) * 64 + (S) * 32, dB + (BUF) * 32768 + (S) * 16384 + 8192);
#define WB8 asm volatile("s_waitcnt vmcnt(8)" ::: "memory"); __builtin_amdgcn_s_barrier();
#define WB4 asm volatile("s_waitcnt vmcnt(4)" ::: "memory"); __builtin_amdgcn_s_barrier();
#define WB0 asm volatile("s_waitcnt vmcnt(0)" ::: "memory"); __builtin_amdgcn_s_barrier();
#define WBN

    bf16x8 bfr[4];

#define PH(BUF, S, RGH, WAITC, STGC)                                          \
    {                                                                         \
        WAITC                                                                 \
        if ((RGH) == 0) {                                                     \
            _Pragma("unroll") for (int cg = 0; cg < 4; cg++)                  \
                bfr[cg] = *(const bf16x8*)(pB0 + (BUF) * 32768 +              \
                                           (S) * 16384 + cg * 1024);          \
        }                                                                     \
        bf16x8 af[4];                                                         \
        _Pragma("unroll") for (int i = 0; i < 4; i++)                         \
            af[i] = *(const bf16x8*)(pA0 + (BUF) * 32768 + (S) * 16384 +      \
                                     ((RGH) * 4 + i) * 1024);                 \
        STGC                                                                  \
        __builtin_amdgcn_s_barrier();                                         \
        asm volatile("s_waitcnt lgkmcnt(0)" ::: "memory");                    \
        __builtin_amdgcn_sched_barrier(0);                                    \
        __builtin_amdgcn_s_setprio(1);                                        \
        _Pragma("unroll") for (int i = 0; i < 4; i++)                         \
            _Pragma("unroll") for (int cg = 0; cg < 4; cg++)                  \
                acc[(RGH) * 4 + i][cg] =                                      \
                    mfma16(af[i], bfr[cg], acc[(RGH) * 4 + i][cg]);           \
        __builtin_amdgcn_s_setprio(0);                                        \
    }

#define TILEF(T, BUF)                                                         \
    PH(BUF, 0, 0, WB8, STGA(T + 1, 1, BUF ^ 1))                               \
    PH(BUF, 0, 1, WBN, STGB(T + 1, 1, BUF ^ 1))                               \
    PH(BUF, 1, 0, WB8, STGA(T + 2, 0, BUF))                                   \
    PH(BUF, 1, 1, WBN, STGB(T + 2, 0, BUF))

    STGA(0, 0, 0) STGB(0, 0, 0) STGA(0, 1, 0) STGB(0, 1, 0)
    STGA(1, 0, 1) STGB(1, 0, 1)

    TILEF(0, 0) TILEF(1, 1) TILEF(2, 0) TILEF(3, 1) TILEF(4, 0) TILEF(5, 1)
    PH(0, 0, 0, WB8, STGA(7, 1, 1))
    PH(0, 0, 1, WBN, STGB(7, 1, 1))
    PH(0, 1, 0, WB8, )
    PH(0, 1, 1, WBN, )
    PH(1, 0, 0, WB4, )
    PH(1, 0, 1, WBN, )
    PH(1, 1, 0, WB0, )
    PH(1, 1, 1, WBN, )
#undef TILEF
#undef PH
#undef WB8
#undef WB4
#undef WB0
#undef WBN
#undef STGA
#undef STGB

    // epilogue: relu + 2-pass LDS bounce (rows 0-127, 128-255)
    float bz[4];
#pragma unroll
    for (int cg = 0; cg < 4; cg++) bz[cg] = bias[n0 + wn * 64 + cg * 16 + l15];
#pragma unroll
    for (int h2 = 0; h2 < 2; h2++) {
        __syncthreads();
        if (wm == h2) {
#pragma unroll
            for (int rg = 0; rg < 8; rg++)
#pragma unroll
                for (int cg = 0; cg < 4; cg++)
#pragma unroll
                    for (int j = 0; j < 4; j++) {
                        int rl = rg * 16 + lg * 4 + j;
                        int cl = wn * 64 + cg * 16 + l15;
                        float v = fmaxf(acc[rg][cg][j] + bz[cg], 0.f);
                        *(bf16*)(sL + rl * 520 + cl * 2) = (bf16)v;
                    }
        }
        __syncthreads();
        int cch = tid & 31, rof = tid >> 5;
#pragma unroll
        for (int p = 0; p < 8; p++) {
            int row = p * 16 + rof;
            bf16x8 vv = *(const bf16x8*)(sL + row * 520 + cch * 16);
            *(bf16x8*)(outb + (size_t)(m0 + h2 * 128 + row) * 2048 +
                       n0 + cch * 8) = vv;
        }
    }
}

// ---------------------------------------------------------------
// Flash attention v14: v11 + KVBLK=128 (two 64-row KV tiles per barrier
// pair). LDS 64KB (2buf x 2sub x {K 8KB | V 8KB}); 2 blocks/CU unchanged;
// counted vmcnt(4); compute = same sequence as v11 run twice with a
// compile-time subtile offset -> numerically identical to v11.
__global__ __launch_bounds__(512, 4)
void k_attn(const bf16* __restrict__ qkvb, const bf16* __restrict__ vt,
            bf16* __restrict__ attno) {
    __shared__ bf16 sK[2][2][64 * 64];   // [buf][sub]
    __shared__ bf16 sV[2][2][64 * 64];
    const float sc = 0.044194173824159216f * 1.4426950408889634f; // 1/sqrt(512)*log2e
    int bid = blockIdx.x;
    int nb = (bid & 7) * 64 + (bid >> 3);     // XCD swizzle: 2 bh per XCD
    int bh = nb >> 5, qt = nb & 31;
    int b = bh >> 3, hh = bh & 7;
    int q0 = qt * 128;
    int tid = threadIdx.x, w = tid >> 6, l = tid & 63;
    int l15 = l & 15, lg = l >> 4, l7 = l15 & 7;
    int vperm = ((lg & 1) << 1) | (lg >> 1);
    const bf16* qbase = qkvb + (size_t)b * 4096 * 1536 + hh * 64;
    const bf16* kbase = qbase + 512;
    const bf16* vbase = vt + (size_t)bh * 64 * 4096;
    int srow = tid >> 3, sphys = tid & 7;     // srow 0..63: full 64-row tile

    const char* kp0 = (const char*)&sK[0][0][0] + l15 * 128 + ((lg ^ l7) << 4);
    const char* kp1 = (const char*)&sK[0][0][0] + l15 * 128 + (((4 + lg) ^ l7) << 4);
    const char* vp0 = (const char*)&sV[0][0][0] + l15 * 128 + ((vperm ^ l7) << 4);
    const char* vp1 = (const char*)&sV[0][0][0] + l15 * 128 + (((4 + vperm) ^ l7) << 4);
    char* dK0 = (char*)&sK[0][0][0] + tid * 16;  // 512 thr x 16B = one 8KB sub
    char* dV0 = (char*)&sV[0][0][0] + tid * 16;
    const char* kg = (const char*)(kbase + srow * 1536 + (sphys ^ (srow & 7)) * 8);
    const char* vg = (const char*)(vbase + srow * 4096 + (sphys ^ (srow & 7)) * 8);

    // prologue: stage KV pair 0 (tiles 0,1) -> buf0
    gload16(kg, dK0);
    gload16(kg + 196608, dK0 + 8192);
    gload16(vg, dV0);
    gload16(vg + 128, dV0 + 8192);
    kg += 393216;
    vg += 256;

    bf16x8 qf[2];
#pragma unroll
    for (int ks = 0; ks < 2; ks++) {
        bf16x8 v = *(const bf16x8*)(qbase +
            (size_t)(q0 + w * 16 + l15) * 1536 + ks * 32 + lg * 8);
        bf16x8 o;
#pragma unroll
        for (int j = 0; j < 8; j++) o[j] = (bf16)((float)v[j] * sc);
        qf[ks] = o;
    }
    bf16x8 ones;
#pragma unroll
    for (int j = 0; j < 8; j++) ones[j] = (bf16)1.0f;

    const f32x4 kZ = {0.f, 0.f, 0.f, 0.f};
    f32x4 accl = kZ;
    f32x4 acc[4];
#pragma unroll
    for (int df = 0; df < 4; df++) acc[df] = kZ;

// one 64-row KV subtile: identical op sequence to v11's compute
#define ACOMP(OFS)                                                            \
    {                                                                         \
        f32x4 s0, s1, s2, s3;                                                 \
        __builtin_amdgcn_s_setprio(1);                                        \
        s0 = mfma16(*(const bf16x8*)(kp0 + (OFS) + 0 * 2048), qf[0], kZ);     \
        s0 = mfma16(*(const bf16x8*)(kp1 + (OFS) + 0 * 2048), qf[1], s0);     \
        s1 = mfma16(*(const bf16x8*)(kp0 + (OFS) + 1 * 2048), qf[0], kZ);     \
        s1 = mfma16(*(const bf16x8*)(kp1 + (OFS) + 1 * 2048), qf[1], s1);     \
        __builtin_amdgcn_s_setprio(0);                                        \
        float e0 = rexp2(s0[0]), e1 = rexp2(s0[1]);                           \
        float e2 = rexp2(s0[2]), e3 = rexp2(s0[3]);                           \
        float e4 = rexp2(s1[0]), e5 = rexp2(s1[1]);                           \
        float e6 = rexp2(s1[2]), e7 = rexp2(s1[3]);                           \
        __builtin_amdgcn_s_setprio(1);                                        \
        s2 = mfma16(*(const bf16x8*)(kp0 + (OFS) + 2 * 2048), qf[0], kZ);     \
        s2 = mfma16(*(const bf16x8*)(kp1 + (OFS) + 2 * 2048), qf[1], s2);     \
        s3 = mfma16(*(const bf16x8*)(kp0 + (OFS) + 3 * 2048), qf[0], kZ);     \
        s3 = mfma16(*(const bf16x8*)(kp1 + (OFS) + 3 * 2048), qf[1], s3);     \
        __builtin_amdgcn_s_setprio(0);                                        \
        int p0 = cvtpk(e0, e1), p1 = cvtpk(e2, e3);                           \
        int p2 = cvtpk(e4, e5), p3 = cvtpk(e6, e7);                           \
        asm("v_permlane16_swap_b32 %0, %1" : "+v"(p2), "+v"(p0));             \
        asm("v_permlane16_swap_b32 %0, %1" : "+v"(p3), "+v"(p1));             \
        {                                                                     \
            int4v ai = {p0, p1, p2, p3};                                      \
            bf16x8 af = __builtin_bit_cast(bf16x8, ai);                       \
            __builtin_amdgcn_s_setprio(1);                                    \
            acc[0] = mfma16(af, *(const bf16x8*)(vp0 + (OFS) + 0 * 2048), acc[0]); \
            acc[1] = mfma16(af, *(const bf16x8*)(vp0 + (OFS) + 1 * 2048), acc[1]); \
            acc[2] = mfma16(af, *(const bf16x8*)(vp0 + (OFS) + 2 * 2048), acc[2]); \
            acc[3] = mfma16(af, *(const bf16x8*)(vp0 + (OFS) + 3 * 2048), acc[3]); \
            accl = mfma16(af, ones, accl);                                    \
            __builtin_amdgcn_s_setprio(0);                                    \
        }                                                                     \
        float e8 = rexp2(s2[0]), e9 = rexp2(s2[1]);                           \
        float e10 = rexp2(s2[2]), e11 = rexp2(s2[3]);                         \
        float e12 = rexp2(s3[0]), e13 = rexp2(s3[1]);                         \
        float e14 = rexp2(s3[2]), e15 = rexp2(s3[3]);                         \
        int p4 = cvtpk(e8, e9), p5 = cvtpk(e10, e11);                         \
        int p6 = cvtpk(e12, e13), p7 = cvtpk(e14, e15);                       \
        asm("v_permlane16_swap_b32 %0, %1" : "+v"(p6), "+v"(p4));             \
        asm("v_permlane16_swap_b32 %0, %1" : "+v"(p7), "+v"(p5));             \
        {                                                                     \
            int4v ai = {p4, p5, p6, p7};                                      \
            bf16x8 af = __builtin_bit_cast(bf16x8, ai);                       \
            __builtin_amdgcn_s_setprio(1);                                    \
            acc[0] = mfma16(af, *(const bf16x8*)(vp1 + (OFS) + 0 * 2048), acc[0]); \
            acc[1] = mfma16(af, *(const bf16x8*)(vp1 + (OFS) + 1 * 2048), acc[1]); \
            acc[2] = mfma16(af, *(const bf16x8*)(vp1 + (OFS) + 2 * 2048), acc[2]); \
            acc[3] = mfma16(af, *(const bf16x8*)(vp1 + (OFS) + 3 * 2048), acc[3]); \
            accl = mfma16(af, ones, accl);                                    \
            __builtin_amdgcn_s_setprio(0);                                    \
        }                                                                     \
    }

#define ABODY2(BUF, PF)                                                       \
    {                                                                         \
        if (PF) {                                                             \
            gload16(kg, dK0 + (1 - (BUF)) * 16384);                           \
            gload16(kg + 196608, dK0 + (1 - (BUF)) * 16384 + 8192);           \
            gload16(vg, dV0 + (1 - (BUF)) * 16384);                           \
            gload16(vg + 128, dV0 + (1 - (BUF)) * 16384 + 8192);              \
            kg += 393216;                                                     \
            vg += 256;                                                        \
            asm volatile("s_waitcnt vmcnt(4)" ::: "memory");                  \
        } else {                                                              \
            asm volatile("s_waitcnt vmcnt(0)" ::: "memory");                  \
        }                                                                     \
        __builtin_amdgcn_s_barrier();                                         \
        __builtin_amdgcn_sched_barrier(0);                                    \
        ACOMP((BUF) * 16384)                                                  \
        ACOMP((BUF) * 16384 + 8192)                                           \
        __builtin_amdgcn_s_barrier();                                         \
    }

    // 32 pair-iters total (64 KV tiles)
    for (int tt = 0; tt < 15; tt++) {
        ABODY2(0, 1)
        ABODY2(1, 1)
    }
    ABODY2(0, 1)
    ABODY2(1, 0)
#undef ABODY2
#undef ACOMP

    float invq[4];
#pragma unroll
    for (int j = 0; j < 4; j++) invq[j] = 1.0f / accl[j];

    // 8 waves x 2KB fit easily in the 32KB sK region
    bf16* ow = (bf16*)&sK[0][0][0] + w * 16 * 64;
#pragma unroll
    for (int df = 0; df < 4; df++) {
        int chunk = df * 2 + (l15 >> 3);
        int within = l15 & 7;
#pragma unroll
        for (int j = 0; j < 4; j++) {
            int q = lg * 4 + j;
            *(bf16*)((char*)ow + q * 128 + ((chunk ^ (q & 7)) << 4) + within * 2) =
                (bf16)(acc[df][j] * invq[j]);
        }
    }
    __syncthreads();
    const char* owr = (const char*)ow;
#pragma unroll
    for (int half = 0; half < 2; half++) {
        int r = l >> 2, ch = (l & 3) + half * 4;
        bf16x8 vv = *(const bf16x8*)(owr + r * 128 + ((ch ^ (r & 7)) << 4));
        *(bf16x8*)(attno + (size_t)(b * 4096 + q0 + w * 16 + r) * 512 +
                   hh * 64 + ch * 8) = vv;
    }
}

// ---------------------------------------------------------------
extern "C" void kernel_launch(void* const* d_in, const int* in_sizes, int n_in,
                              void* d_out, int out_size, void* d_ws, size_t ws_size,
                              hipStream_t stream) {
    const float* x = (const float*)d_in[0];
    const float* ln1g = (const float*)d_in[1];
    const float* ln1b = (const float*)d_in[2];
    const float* wqkv = (const float*)d_in[3];
    const float* bqkv = (const float*)d_in[4];
    const float* wproj = (const float*)d_in[5];
    const float* bproj = (const float*)d_in[6];
    const float* ln2g = (const float*)d_in[7];
    const float* ln2b = (const float*)d_in[8];
    const float* wffn1 = (const float*)d_in[9];
    const float* bffn1 = (const float*)d_in[10];
    const float* wffn2 = (const float*)d_in[11];
    const float* bffn2 = (const float*)d_in[12];
    float* y = (float*)d_out;

    char* ws = (char*)d_ws;
    bf16* po   = (bf16*)(ws + 0);             // 8.4M, live to end
    bf16* h    = (bf16*)(ws + 16777216);      // h1 / attno / h2 (sequential)
    bf16* qkvb = (bf16*)(ws + 25165824);      // 24M
    bf16* vtb  = (bf16*)(ws + 50331648);      // 8M
    bf16* f1   = (bf16*)(ws + 25165824);      // alias qkv+vt (dead after attn)
    bf16* wqT  = (bf16*)(ws + 58720256);
    bf16* wpT  = (bf16*)(ws + 60293120);
    bf16* w1T  = (bf16*)(ws + 60817408);
    bf16* w2T  = (bf16*)(ws + 62914560);
    bf16* attno = h;

    k_pre<<<3328, 512, 0, stream>>>(x, ln1g, ln1b, h,
                                    wqkv, wproj, wffn1, wffn2,
                                    wqT, wpT, w1T, w2T);
    k_gemm<2, 128><<<768, 256, 0, stream>>>(h, wqT, bqkv, qkvb, vtb,
                                            nullptr, nullptr, nullptr,
                                            8192, 1536, 512);
    k_attn<<<512, 512, 0, stream>>>(qkvb, vtb, attno);
    k_gemm<0, 64><<<512, 256, 0, stream>>>(attno, wpT, bproj, po, nullptr,
                                           nullptr, nullptr, nullptr,
                                           8192, 512, 512);
    k_tln2<<<256, 512, 0, stream>>>(x, po, ln2g, ln2b, h);
    k_gemm8<<<256, 512, 0, stream>>>(h, w1T, bffn1, f1);
    k_gemm<3, 64><<<512, 256, 0, stream>>>(f1, w2T, bffn2, nullptr, nullptr,
                                           x, po, y, 8192, 512, 2048);
}

// Round 21
// 170.919 us; speedup vs baseline: 1.0532x; 1.0001x over previous
//
#include <hip/hip_runtime.h>
#include <hip/hip_bf16.h>

typedef __bf16 bf16;
typedef __bf16 bf16x8 __attribute__((ext_vector_type(8)));
typedef __bf16 bf16x4 __attribute__((ext_vector_type(4)));
typedef __bf16 bf16x2 __attribute__((ext_vector_type(2)));
typedef float f32x4 __attribute__((ext_vector_type(4)));
typedef int int4v __attribute__((ext_vector_type(4)));
typedef int int2v __attribute__((ext_vector_type(2)));

#define DEV static __device__ __forceinline__

DEV void gload16(const void* g, void* l) {
    __builtin_amdgcn_global_load_lds(
        (const __attribute__((address_space(1))) void*)g,
        (__attribute__((address_space(3))) void*)l, 16, 0, 0);
}

DEV f32x4 mfma16(bf16x8 a, bf16x8 b, f32x4 c) {
    return __builtin_amdgcn_mfma_f32_16x16x32_bf16(a, b, c, 0, 0, 0);
}

DEV int cvtpk(float lo, float hi) {
    int r;
    asm("v_cvt_pk_bf16_f32 %0, %1, %2" : "=v"(r) : "v"(lo), "v"(hi));
    return r;
}

DEV float rexp2(float x) {   // raw v_exp_f32 (no denormal guard)
    float r;
    asm("v_exp_f32 %0, %1" : "=v"(r) : "v"(x));
    return r;
}

// ---------------------------------------------------------------
// Fused first-stage: blocks 0..255 = transpose+LN1 (h = LN(x^T));
// blocks 256..3327 = the 4 weight transposes (fp32 [K][N] -> bf16 [N][K]).
__global__ __launch_bounds__(512, 2)
void k_pre(const float* __restrict__ x, const float* __restrict__ gg,
           const float* __restrict__ bb, bf16* __restrict__ h,
           const float* __restrict__ w0, const float* __restrict__ w1,
           const float* __restrict__ w2, const float* __restrict__ w3,
           bf16* __restrict__ d0, bf16* __restrict__ d1,
           bf16* __restrict__ d2, bf16* __restrict__ d3) {
    __shared__ char sm[35840];
    int bid = blockIdx.x;
    int t = threadIdx.x;

    if (bid >= 256) {
        float* tile = (float*)sm;              // [32][33]
        int tt = bid - 256;
        const float* w;
        bf16* d;
        int K, N, ti;
        if (tt < 768)       { w = w0; d = d0; K = 512;  N = 1536; ti = tt; }
        else if (tt < 1024) { w = w1; d = d1; K = 512;  N = 512;  ti = tt - 768; }
        else if (tt < 2048) { w = w2; d = d2; K = 512;  N = 2048; ti = tt - 1024; }
        else                { w = w3; d = d3; K = 2048; N = 512;  ti = tt - 2048; }
        int ntn = N >> 5;
        int kt = ti / ntn, ntile = ti % ntn;
        int k0 = kt * 32, n0 = ntile * 32;
        int nl = t & 31, kl = t >> 5;
#pragma unroll
        for (int i = 0; i < 2; i++) {
            int k = kl + i * 16;
            tile[k * 33 + nl] = w[(size_t)(k0 + k) * N + n0 + nl];
        }
        __syncthreads();
        int kl2 = t & 31, nl2 = t >> 5;
#pragma unroll
        for (int i = 0; i < 2; i++) {
            int n = nl2 + i * 16;
            d[(size_t)(n0 + n) * K + k0 + kl2] = (bf16)tile[kl2 * 33 + n];
        }
        return;
    }

    bf16* big = (bf16*)sm;                     // [32][524]
    float* red = (float*)(sm + 33536);         // [8][32][2]
    float* mures = (float*)(sm + 35584);       // [32][2]
    int nt = bid & 127, b = bid >> 7;
    int n0 = nt * 32;

    int n = t & 31, cg = t >> 5;
    const float* xp = x + (size_t)b * 512 * 4096 +
                      (size_t)(cg * 32) * 4096 + n0 + n;
    float s = 0.f, ss = 0.f;
#pragma unroll
    for (int i = 0; i < 32; i++) {
        float v = xp[(size_t)i * 4096];
        s += v;
        ss += v * v;
        big[n * 524 + cg * 32 + i] = (bf16)v;
    }
    s += __shfl_xor(s, 32);
    ss += __shfl_xor(ss, 32);
    int w = t >> 6, l = t & 63;
    if (l < 32) {
        red[(w * 32 + n) * 2] = s;
        red[(w * 32 + n) * 2 + 1] = ss;
    }
    __syncthreads();
    if (t < 32) {
        float ts = 0.f, tss = 0.f;
#pragma unroll
        for (int ww = 0; ww < 8; ww++) {
            ts += red[(ww * 32 + t) * 2];
            tss += red[(ww * 32 + t) * 2 + 1];
        }
        float mu = ts * (1.f / 512.f);
        float var = tss * (1.f / 512.f) - mu * mu;
        mures[t * 2] = mu;
        mures[t * 2 + 1] = rsqrtf(var + 1e-5f);
    }
    __syncthreads();

    int nw = t >> 4, cs = t & 15;
    float mu = mures[nw * 2], rs = mures[nw * 2 + 1];
    bf16* hd = h + (size_t)(b * 4096 + n0 + nw) * 512;
#pragma unroll
    for (int j = 0; j < 4; j++) {
        int c = cs * 8 + j * 128;
        bf16x8 vv = *(const bf16x8*)&big[nw * 524 + c];
        f32x4 g0v = *(const f32x4*)(gg + c);
        f32x4 g1v = *(const f32x4*)(gg + c + 4);
        f32x4 b0v = *(const f32x4*)(bb + c);
        f32x4 b1v = *(const f32x4*)(bb + c + 4);
        bf16x8 o;
#pragma unroll
        for (int k = 0; k < 4; k++) {
            o[k] = (bf16)(((float)vv[k] - mu) * rs * g0v[k] + b0v[k]);
            o[k + 4] = (bf16)(((float)vv[k + 4] - mu) * rs * g1v[k] + b1v[k]);
        }
        *(bf16x8*)(hd + c) = o;
    }
}

// ---------------------------------------------------------------
// Fused residual + transpose + LayerNorm: h[n][c] = LN_c(x^T + po).
__global__ __launch_bounds__(512, 2)
void k_tln2(const float* __restrict__ x, const bf16* __restrict__ po,
            const float* __restrict__ gg, const float* __restrict__ bb,
            bf16* __restrict__ h) {
    __shared__ char sm[69632];
    bf16* big = (bf16*)sm;                     // [32][524]
    float* red = (float*)(sm + 33536);         // [8][32][2]
    float* mures = (float*)(sm + 35584);       // [32][2]
    bf16* pob = (bf16*)(sm + 35840);           // [32][524]

    int t = threadIdx.x;
    int bid = blockIdx.x;
    int nt = bid & 127, b = bid >> 7;
    int n0 = nt * 32;

    {
        int rr = t >> 4, cs16 = t & 15;
        const bf16* ps = po + (size_t)(b * 4096 + n0 + rr) * 512 + cs16 * 32;
#pragma unroll
        for (int j = 0; j < 4; j++)
            *(bf16x8*)&pob[rr * 524 + cs16 * 32 + j * 8] =
                *(const bf16x8*)(ps + j * 8);
        __syncthreads();
    }

    int n = t & 31, cg = t >> 5;
    const float* xp = x + (size_t)b * 512 * 4096 +
                      (size_t)(cg * 32) * 4096 + n0 + n;
    float s = 0.f, ss = 0.f;
#pragma unroll
    for (int i = 0; i < 32; i++) {
        float v = xp[(size_t)i * 4096] + (float)pob[n * 524 + cg * 32 + i];
        s += v;
        ss += v * v;
        big[n * 524 + cg * 32 + i] = (bf16)v;
    }
    s += __shfl_xor(s, 32);
    ss += __shfl_xor(ss, 32);
    int w = t >> 6, l = t & 63;
    if (l < 32) {
        red[(w * 32 + n) * 2] = s;
        red[(w * 32 + n) * 2 + 1] = ss;
    }
    __syncthreads();
    if (t < 32) {
        float ts = 0.f, tss = 0.f;
#pragma unroll
        for (int ww = 0; ww < 8; ww++) {
            ts += red[(ww * 32 + t) * 2];
            tss += red[(ww * 32 + t) * 2 + 1];
        }
        float mu = ts * (1.f / 512.f);
        float var = tss * (1.f / 512.f) - mu * mu;
        mures[t * 2] = mu;
        mures[t * 2 + 1] = rsqrtf(var + 1e-5f);
    }
    __syncthreads();

    int nw = t >> 4, cs = t & 15;
    float mu = mures[nw * 2], rs = mures[nw * 2 + 1];
    bf16* hd = h + (size_t)(b * 4096 + n0 + nw) * 512;
#pragma unroll
    for (int j = 0; j < 4; j++) {
        int c = cs * 8 + j * 128;
        bf16x8 vv = *(const bf16x8*)&big[nw * 524 + c];
        f32x4 g0v = *(const f32x4*)(gg + c);
        f32x4 g1v = *(const f32x4*)(gg + c + 4);
        f32x4 b0v = *(const f32x4*)(bb + c);
        f32x4 b1v = *(const f32x4*)(bb + c + 4);
        bf16x8 o;
#pragma unroll
        for (int k = 0; k < 4; k++) {
            o[k] = (bf16)(((float)vv[k] - mu) * rs * g0v[k] + b0v[k]);
            o[k + 4] = (bf16)(((float)vv[k + 4] - mu) * rs * g1v[k] + b1v[k]);
        }
        *(bf16x8*)(hd + c) = o;
    }
}

// ---------------------------------------------------------------
// GEMM (2-phase): out[M][N](bf16) = A @ BT^T + bias.
// MODE 0 plain / 2 qkv (V-slice transposed into vt) / 3 ffn2+final.
template <int MODE, int BN>
__global__ __launch_bounds__(256, BN == 64 ? 3 : 2)
void k_gemm(const bf16* __restrict__ A, const bf16* __restrict__ BT,
            const float* __restrict__ bias, bf16* __restrict__ outb,
            bf16* __restrict__ vtout, const float* __restrict__ xin,
            const bf16* __restrict__ poin, float* __restrict__ yout,
            int M, int N, int K) {
    constexpr int CG = BN / 32;
    constexpr int BSZ = CG * 4096;
    __shared__ char smem[32768 + 2 * BSZ];
    int ntn = N / BN;
    int nwg = gridDim.x;
    int bid = blockIdx.x;
    int cpx = nwg >> 3;
    bid = (bid & 7) * cpx + (bid >> 3);       // XCD-aware swizzle
    int bm = bid / ntn, bn = bid % ntn;
    int m0 = bm * 128, n0 = bn * BN;
    int tid = threadIdx.x;
    int w = tid >> 6, l = tid & 63;
    int wm = w >> 1, wn = w & 1;
    int l15 = l & 15, lg = l >> 4;

    f32x4 acc[4][CG];
#pragma unroll
    for (int i = 0; i < 4; i++)
#pragma unroll
        for (int j = 0; j < CG; j++) acc[i][j] = (f32x4){0.f, 0.f, 0.f, 0.f};

    int srow = tid >> 3, sphys = tid & 7;
    int lrow_a = wm * 64 + l15;
    int lrow_b = wn * (BN / 2) + l15;

#define GEMM_STAGE(k0v, bb)                                                  \
    do {                                                                     \
        _Pragma("unroll") for (int s = 0; s < 4; s++) {                      \
            int row = s * 32 + srow;                                         \
            int k16 = sphys ^ (row & 7);                                     \
            gload16(A + (size_t)(m0 + row) * K + (k0v) + k16 * 8,            \
                    smem + (bb) * 16384 + s * 4096 + tid * 16);              \
        }                                                                    \
        _Pragma("unroll") for (int s = 0; s < CG; s++) {                     \
            int row = s * 32 + srow;                                         \
            int k16 = sphys ^ (row & 7);                                     \
            gload16(BT + (size_t)(n0 + row) * K + (k0v) + k16 * 8,           \
                    smem + 32768 + (bb) * BSZ + s * 4096 + tid * 16);        \
        }                                                                    \
    } while (0)

    int nk = K >> 6;
    GEMM_STAGE(0, 0);
    int cur = 0;
    for (int kt = 0; kt < nk; kt++) {
        if (kt + 1 < nk) {
            GEMM_STAGE((kt + 1) << 6, cur ^ 1);
            if constexpr (BN == 128)
                asm volatile("s_waitcnt vmcnt(8)" ::: "memory");
            else
                asm volatile("s_waitcnt vmcnt(6)" ::: "memory");
        } else {
            asm volatile("s_waitcnt vmcnt(0)" ::: "memory");
        }
        __builtin_amdgcn_s_barrier();
        __builtin_amdgcn_sched_barrier(0);
        const char* pA = smem + cur * 16384;
        const char* pB = smem + 32768 + cur * BSZ;
#pragma unroll
        for (int ks = 0; ks < 2; ks++) {
            bf16x8 af[4], bfr[CG];
#pragma unroll
            for (int rg = 0; rg < 4; rg++) {
                int row = lrow_a + rg * 16;
                af[rg] = *(const bf16x8*)(pA + row * 128 +
                                          (((lg + ks * 4) ^ (row & 7)) << 4));
            }
#pragma unroll
            for (int cg = 0; cg < CG; cg++) {
                int row = lrow_b + cg * 16;
                bfr[cg] = *(const bf16x8*)(pB + row * 128 +
                                           (((lg + ks * 4) ^ (row & 7)) << 4));
            }
#pragma unroll
            for (int rg = 0; rg < 4; rg++)
#pragma unroll
                for (int cg = 0; cg < CG; cg++)
                    acc[rg][cg] = mfma16(af[rg], bfr[cg], acc[rg][cg]);
        }
        __builtin_amdgcn_s_barrier();
        cur ^= 1;
    }
#undef GEMM_STAGE

    if constexpr (MODE == 2) {
        if (n0 >= 1024) {
            char* vl = smem;        // col-major [BN col][136 row] bf16
#pragma unroll
            for (int cg = 0; cg < CG; cg++) {
                int col = wn * (BN / 2) + cg * 16 + l15;
                float bz = bias[n0 + col];
#pragma unroll
                for (int rg = 0; rg < 4; rg++) {
                    int rowb = wm * 64 + rg * 16 + lg * 4;
                    int2v qq = {cvtpk(acc[rg][cg][0] + bz, acc[rg][cg][1] + bz),
                                cvtpk(acc[rg][cg][2] + bz, acc[rg][cg][3] + bz)};
                    *(int2v*)(vl + col * 272 + rowb * 2) = qq;
                }
            }
            __syncthreads();
            int b = m0 >> 12, nrow0 = m0 & 4095;
            int dl = tid >> 3, c8 = tid & 7;
#pragma unroll
            for (int dd = 0; dd < BN / 32; dd++) {
                int d = dd * 32 + dl;
                int ch = (n0 - 1024) + d;
                bf16* dst = vtout +
                    ((size_t)((b * 8 + (ch >> 6)) * 64 + (ch & 63))) * 4096 + nrow0;
#pragma unroll
                for (int half = 0; half < 2; half++) {
                    int chunk = half * 8 + c8;
                    bf16x8 vv = *(const bf16x8*)(vl + d * 272 + chunk * 16);
                    *(bf16x8*)(dst + chunk * 8) = vv;
                }
            }
            return;
        }
    }

    if constexpr (MODE == 3) {
        // ---- fused final: y[b][c][n] = 2x + po + (acc + bias)
        float* ts = (float*)smem;            // [64 c][132 n] fp32
        int b = m0 >> 12, nrow0 = m0 & 4095;
#pragma unroll
        for (int cg = 0; cg < CG; cg++) {
            int lcol = wn * (BN / 2) + cg * 16 + l15;
            float bz = bias[n0 + lcol];
#pragma unroll
            for (int rg = 0; rg < 4; rg++) {
#pragma unroll
                for (int j = 0; j < 4; j++) {
                    int lrow = wm * 64 + rg * 16 + lg * 4 + j;
                    float v = acc[rg][cg][j] + bz +
                        (float)poin[(size_t)(m0 + lrow) * 512 + n0 + lcol];
                    ts[lcol * 132 + lrow] = v;
                }
            }
        }
        __syncthreads();
        int nl = (tid & 31) * 4, chh = tid >> 5;
#pragma unroll
        for (int q = 0; q < 8; q++) {
            int c = chh + q * 8;
            size_t off = ((size_t)b * 512 + n0 + c) * 4096 + nrow0 + nl;
            f32x4 xv = *(const f32x4*)(xin + off);
            f32x4 tv = *(const f32x4*)&ts[c * 132 + nl];
            f32x4 ov;
#pragma unroll
            for (int k2 = 0; k2 < 4; k2++) ov[k2] = 2.f * xv[k2] + tv[k2];
            *(f32x4*)(yout + off) = ov;
        }
        return;
    }

    constexpr int RS = BN * 2 + 8;
    constexpr int CH = BN / 8;
    char* ep = smem;
#pragma unroll
    for (int cg = 0; cg < CG; cg++) {
        int lcol = wn * (BN / 2) + cg * 16 + l15;
        float bz = bias[n0 + lcol];
#pragma unroll
        for (int rg = 0; rg < 4; rg++) {
#pragma unroll
            for (int j = 0; j < 4; j++) {
                int lrow = wm * 64 + rg * 16 + lg * 4 + j;
                float v = acc[rg][cg][j] + bz;
                *(bf16*)(ep + lrow * RS + lcol * 2) = (bf16)v;
            }
        }
    }
    __syncthreads();
    int cch = tid & (CH - 1);
    int rof = tid / CH;
    constexpr int RPP = 256 / CH;
#pragma unroll
    for (int i = 0; i < 128 / RPP; i++) {
        int row = i * RPP + rof;
        bf16x8 vv = *(const bf16x8*)(ep + row * RS + cch * 16);
        *(bf16x8*)(outb + (size_t)(m0 + row) * N + n0 + cch * 8) = vv;
    }
}

// ---------------------------------------------------------------
// FFN1 GEMM, 8-phase 256^2 schedule (T3+T4): M=8192 N=2048 K=512, relu.
__global__ __launch_bounds__(512, 2)
void k_gemm8(const bf16* __restrict__ A, const bf16* __restrict__ BT,
             const float* __restrict__ bias, bf16* __restrict__ outb) {
    __shared__ char sL[131072];   // A: [2buf][2s][256r][64B] @0; B same @65536
    int bid = blockIdx.x;
    bid = (bid & 7) * 32 + (bid >> 3);        // XCD swizzle (grid 256)
    int bm = bid >> 3, bn = bid & 7;
    int m0 = bm * 256, n0 = bn * 256;
    int tid = threadIdx.x;
    int w = tid >> 6, l = tid & 63;
    int wm = w >> 2, wn = w & 3;              // 2M x 4N waves
    int l15 = l & 15, lg = l >> 4;
    int cpr = (lg ^ ((l15 >> 1) & 3)) << 4;   // read chunk byte-offset (lane-inv)

    f32x4 acc[8][4];
#pragma unroll
    for (int i = 0; i < 8; i++)
#pragma unroll
        for (int j = 0; j < 4; j++) acc[i][j] = (f32x4){0.f, 0.f, 0.f, 0.f};

    int srow = tid >> 2, scp = tid & 3;
    int kofs = (scp ^ ((srow >> 1) & 3)) * 8;
    const bf16* gA0 = A + (size_t)(m0 + srow) * 512 + kofs;
    const bf16* gA1 = gA0 + 128 * 512;
    const bf16* gB0 = BT + (size_t)(n0 + srow) * 512 + kofs;
    const bf16* gB1 = gB0 + 128 * 512;
    char* dA = sL + tid * 16;
    char* dB = sL + 65536 + tid * 16;
    const char* pA0 = sL + (wm * 128 + l15) * 64 + cpr;
    const char* pB0 = sL + 65536 + (wn * 64 + l15) * 64 + cpr;

#define STGA(T, S, BUF)                                                       \
    gload16(gA0 + (T) * 64 + (S) * 32, dA + (BUF) * 32768 + (S) * 16384);     \
    gload16(gA1 + (T) * 64 + (S) * 32, dA + (BUF) * 32768 + (S) * 16384 + 8192);
#define STGB(T, S, BUF)                                                       \
    gload16(gB0 + (T) * 64 + (S) * 32, dB + (BUF) * 32768 + (S) * 16384);     \
    gload16(gB1 + (T) * 64 + (S) * 32, dB + (BUF) * 32768 + (S) * 16384 + 8192);
#define WB8 asm volatile("s_waitcnt vmcnt(8)" ::: "memory"); __builtin_amdgcn_s_barrier();
#define WB4 asm volatile("s_waitcnt vmcnt(4)" ::: "memory"); __builtin_amdgcn_s_barrier();
#define WB0 asm volatile("s_waitcnt vmcnt(0)" ::: "memory"); __builtin_amdgcn_s_barrier();
#define WBN

    bf16x8 bfr[4];

#define PH(BUF, S, RGH, WAITC, STGC)                                          \
    {                                                                         \
        WAITC                                                                 \
        if ((RGH) == 0) {                                                     \
            _Pragma("unroll") for (int cg = 0; cg < 4; cg++)                  \
                bfr[cg] = *(const bf16x8*)(pB0 + (BUF) * 32768 +              \
                                           (S) * 16384 + cg * 1024);          \
        }                                                                     \
        bf16x8 af[4];                                                         \
        _Pragma("unroll") for (int i = 0; i < 4; i++)                         \
            af[i] = *(const bf16x8*)(pA0 + (BUF) * 32768 + (S) * 16384 +      \
                                     ((RGH) * 4 + i) * 1024);                 \
        STGC                                                                  \
        __builtin_amdgcn_s_barrier();                                         \
        asm volatile("s_waitcnt lgkmcnt(0)" ::: "memory");                    \
        __builtin_amdgcn_sched_barrier(0);                                    \
        __builtin_amdgcn_s_setprio(1);                                        \
        _Pragma("unroll") for (int i = 0; i < 4; i++)                         \
            _Pragma("unroll") for (int cg = 0; cg < 4; cg++)                  \
                acc[(RGH) * 4 + i][cg] =                                      \
                    mfma16(af[i], bfr[cg], acc[(RGH) * 4 + i][cg]);           \
        __builtin_amdgcn_s_setprio(0);                                        \
    }

#define TILEF(T, BUF)                                                         \
    PH(BUF, 0, 0, WB8, STGA(T + 1, 1, BUF ^ 1))                               \
    PH(BUF, 0, 1, WBN, STGB(T + 1, 1, BUF ^ 1))                               \
    PH(BUF, 1, 0, WB8, STGA(T + 2, 0, BUF))                                   \
    PH(BUF, 1, 1, WBN, STGB(T + 2, 0, BUF))

    STGA(0, 0, 0) STGB(0, 0, 0) STGA(0, 1, 0) STGB(0, 1, 0)
    STGA(1, 0, 1) STGB(1, 0, 1)

    TILEF(0, 0) TILEF(1, 1) TILEF(2, 0) TILEF(3, 1) TILEF(4, 0) TILEF(5, 1)
    PH(0, 0, 0, WB8, STGA(7, 1, 1))
    PH(0, 0, 1, WBN, STGB(7, 1, 1))
    PH(0, 1, 0, WB8, )
    PH(0, 1, 1, WBN, )
    PH(1, 0, 0, WB4, )
    PH(1, 0, 1, WBN, )
    PH(1, 1, 0, WB0, )
    PH(1, 1, 1, WBN, )
#undef TILEF
#undef PH
#undef WB8
#undef WB4
#undef WB0
#undef WBN
#undef STGA
#undef STGB

    // epilogue: relu + 2-pass LDS bounce (rows 0-127, 128-255)
    float bz[4];
#pragma unroll
    for (int cg = 0; cg < 4; cg++) bz[cg] = bias[n0 + wn * 64 + cg * 16 + l15];
#pragma unroll
    for (int h2 = 0; h2 < 2; h2++) {
        __syncthreads();
        if (wm == h2) {
#pragma unroll
            for (int rg = 0; rg < 8; rg++)
#pragma unroll
                for (int cg = 0; cg < 4; cg++)
#pragma unroll
                    for (int j = 0; j < 4; j++) {
                        int rl = rg * 16 + lg * 4 + j;
                        int cl = wn * 64 + cg * 16 + l15;
                        float v = fmaxf(acc[rg][cg][j] + bz[cg], 0.f);
                        *(bf16*)(sL + rl * 520 + cl * 2) = (bf16)v;
                    }
        }
        __syncthreads();
        int cch = tid & 31, rof = tid >> 5;
#pragma unroll
        for (int p = 0; p < 8; p++) {
            int row = p * 16 + rof;
            bf16x8 vv = *(const bf16x8*)(sL + row * 520 + cch * 16);
            *(bf16x8*)(outb + (size_t)(m0 + h2 * 128 + row) * 2048 +
                       n0 + cch * 8) = vv;
        }
    }
}

// ---------------------------------------------------------------
// Flash attention v15: v14 (KVBLK=128) + single-barrier double-buffer:
// iter t = {vmcnt(0); barrier; stage pair t+1 -> buf^1; compute pair t
// from buf}. One barrier per 128 KV rows. Ordering: data-ready via
// vmcnt(0)+barrier (stage had a full compute phase to land); WAR via the
// same barrier (buf^1 last read in iter t-1). Numerically identical.
__global__ __launch_bounds__(512, 4)
void k_attn(const bf16* __restrict__ qkvb, const bf16* __restrict__ vt,
            bf16* __restrict__ attno) {
    __shared__ bf16 sK[2][2][64 * 64];   // [buf][sub]
    __shared__ bf16 sV[2][2][64 * 64];
    const float sc = 0.044194173824159216f * 1.4426950408889634f; // 1/sqrt(512)*log2e
    int bid = blockIdx.x;
    int nb = (bid & 7) * 64 + (bid >> 3);     // XCD swizzle: 2 bh per XCD
    int bh = nb >> 5, qt = nb & 31;
    int b = bh >> 3, hh = bh & 7;
    int q0 = qt * 128;
    int tid = threadIdx.x, w = tid >> 6, l = tid & 63;
    int l15 = l & 15, lg = l >> 4, l7 = l15 & 7;
    int vperm = ((lg & 1) << 1) | (lg >> 1);
    const bf16* qbase = qkvb + (size_t)b * 4096 * 1536 + hh * 64;
    const bf16* kbase = qbase + 512;
    const bf16* vbase = vt + (size_t)bh * 64 * 4096;
    int srow = tid >> 3, sphys = tid & 7;     // srow 0..63: full 64-row tile

    const char* kp0 = (const char*)&sK[0][0][0] + l15 * 128 + ((lg ^ l7) << 4);
    const char* kp1 = (const char*)&sK[0][0][0] + l15 * 128 + (((4 + lg) ^ l7) << 4);
    const char* vp0 = (const char*)&sV[0][0][0] + l15 * 128 + ((vperm ^ l7) << 4);
    const char* vp1 = (const char*)&sV[0][0][0] + l15 * 128 + (((4 + vperm) ^ l7) << 4);
    char* dK0 = (char*)&sK[0][0][0] + tid * 16;  // 512 thr x 16B = one 8KB sub
    char* dV0 = (char*)&sV[0][0][0] + tid * 16;
    const char* kg = (const char*)(kbase + srow * 1536 + (sphys ^ (srow & 7)) * 8);
    const char* vg = (const char*)(vbase + srow * 4096 + (sphys ^ (srow & 7)) * 8);

    // qf loads first so the prologue vmcnt(0) drains them too
    bf16x8 qf[2];
#pragma unroll
    for (int ks = 0; ks < 2; ks++) {
        bf16x8 v = *(const bf16x8*)(qbase +
            (size_t)(q0 + w * 16 + l15) * 1536 + ks * 32 + lg * 8);
        bf16x8 o;
#pragma unroll
        for (int j = 0; j < 8; j++) o[j] = (bf16)((float)v[j] * sc);
        qf[ks] = o;
    }

    // prologue: stage KV pair 0 (tiles 0,1) -> buf0
    gload16(kg, dK0);
    gload16(kg + 196608, dK0 + 8192);
    gload16(vg, dV0);
    gload16(vg + 128, dV0 + 8192);
    kg += 393216;
    vg += 256;

    bf16x8 ones;
#pragma unroll
    for (int j = 0; j < 8; j++) ones[j] = (bf16)1.0f;

    const f32x4 kZ = {0.f, 0.f, 0.f, 0.f};
    f32x4 accl = kZ;
    f32x4 acc[4];
#pragma unroll
    for (int df = 0; df < 4; df++) acc[df] = kZ;

// one 64-row KV subtile: identical op sequence to v11/v14 compute
#define ACOMP(OFS)                                                            \
    {                                                                         \
        f32x4 s0, s1, s2, s3;                                                 \
        __builtin_amdgcn_s_setprio(1);                                        \
        s0 = mfma16(*(const bf16x8*)(kp0 + (OFS) + 0 * 2048), qf[0], kZ);     \
        s0 = mfma16(*(const bf16x8*)(kp1 + (OFS) + 0 * 2048), qf[1], s0);     \
        s1 = mfma16(*(const bf16x8*)(kp0 + (OFS) + 1 * 2048), qf[0], kZ);     \
        s1 = mfma16(*(const bf16x8*)(kp1 + (OFS) + 1 * 2048), qf[1], s1);     \
        __builtin_amdgcn_s_setprio(0);                                        \
        float e0 = rexp2(s0[0]), e1 = rexp2(s0[1]);                           \
        float e2 = rexp2(s0[2]), e3 = rexp2(s0[3]);                           \
        float e4 = rexp2(s1[0]), e5 = rexp2(s1[1]);                           \
        float e6 = rexp2(s1[2]), e7 = rexp2(s1[3]);                           \
        __builtin_amdgcn_s_setprio(1);                                        \
        s2 = mfma16(*(const bf16x8*)(kp0 + (OFS) + 2 * 2048), qf[0], kZ);     \
        s2 = mfma16(*(const bf16x8*)(kp1 + (OFS) + 2 * 2048), qf[1], s2);     \
        s3 = mfma16(*(const bf16x8*)(kp0 + (OFS) + 3 * 2048), qf[0], kZ);     \
        s3 = mfma16(*(const bf16x8*)(kp1 + (OFS) + 3 * 2048), qf[1], s3);     \
        __builtin_amdgcn_s_setprio(0);                                        \
        int p0 = cvtpk(e0, e1), p1 = cvtpk(e2, e3);                           \
        int p2 = cvtpk(e4, e5), p3 = cvtpk(e6, e7);                           \
        asm("v_permlane16_swap_b32 %0, %1" : "+v"(p2), "+v"(p0));             \
        asm("v_permlane16_swap_b32 %0, %1" : "+v"(p3), "+v"(p1));             \
        {                                                                     \
            int4v ai = {p0, p1, p2, p3};                                      \
            bf16x8 af = __builtin_bit_cast(bf16x8, ai);                       \
            __builtin_amdgcn_s_setprio(1);                                    \
            acc[0] = mfma16(af, *(const bf16x8*)(vp0 + (OFS) + 0 * 2048), acc[0]); \
            acc[1] = mfma16(af, *(const bf16x8*)(vp0 + (OFS) + 1 * 2048), acc[1]); \
            acc[2] = mfma16(af, *(const bf16x8*)(vp0 + (OFS) + 2 * 2048), acc[2]); \
            acc[3] = mfma16(af, *(const bf16x8*)(vp0 + (OFS) + 3 * 2048), acc[3]); \
            accl = mfma16(af, ones, accl);                                    \
            __builtin_amdgcn_s_setprio(0);                                    \
        }                                                                     \
        float e8 = rexp2(s2[0]), e9 = rexp2(s2[1]);                           \
        float e10 = rexp2(s2[2]), e11 = rexp2(s2[3]);                         \
        float e12 = rexp2(s3[0]), e13 = rexp2(s3[1]);                         \
        float e14 = rexp2(s3[2]), e15 = rexp2(s3[3]);                         \
        int p4 = cvtpk(e8, e9), p5 = cvtpk(e10, e11);                         \
        int p6 = cvtpk(e12, e13), p7 = cvtpk(e14, e15);                       \
        asm("v_permlane16_swap_b32 %0, %1" : "+v"(p6), "+v"(p4));             \
        asm("v_permlane16_swap_b32 %0, %1" : "+v"(p7), "+v"(p5));             \
        {                                                                     \
            int4v ai = {p4, p5, p6, p7};                                      \
            bf16x8 af = __builtin_bit_cast(bf16x8, ai);                       \
            __builtin_amdgcn_s_setprio(1);                                    \
            acc[0] = mfma16(af, *(const bf16x8*)(vp1 + (OFS) + 0 * 2048), acc[0]); \
            acc[1] = mfma16(af, *(const bf16x8*)(vp1 + (OFS) + 1 * 2048), acc[1]); \
            acc[2] = mfma16(af, *(const bf16x8*)(vp1 + (OFS) + 2 * 2048), acc[2]); \
            acc[3] = mfma16(af, *(const bf16x8*)(vp1 + (OFS) + 3 * 2048), acc[3]); \
            accl = mfma16(af, ones, accl);                                    \
            __builtin_amdgcn_s_setprio(0);                                    \
        }                                                                     \
    }

// single-barrier iteration: drain own loads, sync, stage next, compute
#define ABODY1(BUF, PF)                                                       \
    {                                                                         \
        asm volatile("s_waitcnt vmcnt(0)" ::: "memory");                      \
        __builtin_amdgcn_s_barrier();                                         \
        __builtin_amdgcn_sched_barrier(0);                                    \
        if (PF) {                                                             \
            gload16(kg, dK0 + (1 - (BUF)) * 16384);                           \
            gload16(kg + 196608, dK0 + (1 - (BUF)) * 16384 + 8192);           \
            gload16(vg, dV0 + (1 - (BUF)) * 16384);                           \
            gload16(vg + 128, dV0 + (1 - (BUF)) * 16384 + 8192);              \
            kg += 393216;                                                     \
            vg += 256;                                                        \
        }                                                                     \
        ACOMP((BUF) * 16384)                                                  \
        ACOMP((BUF) * 16384 + 8192)                                           \
    }

    // 32 pair-iters total (64 KV tiles)
    for (int tt = 0; tt < 15; tt++) {
        ABODY1(0, 1)
        ABODY1(1, 1)
    }
    ABODY1(0, 1)
    ABODY1(1, 0)
#undef ABODY1
#undef ACOMP

    float invq[4];
#pragma unroll
    for (int j = 0; j < 4; j++) invq[j] = 1.0f / accl[j];

    // epilogue bounce targets buf0 (disjoint from buf1, which the last
    // iteration read); pre-read __syncthreads below orders the read-back.
    bf16* ow = (bf16*)&sK[0][0][0] + w * 16 * 64;
#pragma unroll
    for (int df = 0; df < 4; df++) {
        int chunk = df * 2 + (l15 >> 3);
        int within = l15 & 7;
#pragma unroll
        for (int j = 0; j < 4; j++) {
            int q = lg * 4 + j;
            *(bf16*)((char*)ow + q * 128 + ((chunk ^ (q & 7)) << 4) + within * 2) =
                (bf16)(acc[df][j] * invq[j]);
        }
    }
    __syncthreads();
    const char* owr = (const char*)ow;
#pragma unroll
    for (int half = 0; half < 2; half++) {
        int r = l >> 2, ch = (l & 3) + half * 4;
        bf16x8 vv = *(const bf16x8*)(owr + r * 128 + ((ch ^ (r & 7)) << 4));
        *(bf16x8*)(attno + (size_t)(b * 4096 + q0 + w * 16 + r) * 512 +
                   hh * 64 + ch * 8) = vv;
    }
}

// ---------------------------------------------------------------
extern "C" void kernel_launch(void* const* d_in, const int* in_sizes, int n_in,
                              void* d_out, int out_size, void* d_ws, size_t ws_size,
                              hipStream_t stream) {
    const float* x = (const float*)d_in[0];
    const float* ln1g = (const float*)d_in[1];
    const float* ln1b = (const float*)d_in[2];
    const float* wqkv = (const float*)d_in[3];
    const float* bqkv = (const float*)d_in[4];
    const float* wproj = (const float*)d_in[5];
    const float* bproj = (const float*)d_in[6];
    const float* ln2g = (const float*)d_in[7];
    const float* ln2b = (const float*)d_in[8];
    const float* wffn1 = (const float*)d_in[9];
    const float* bffn1 = (const float*)d_in[10];
    const float* wffn2 = (const float*)d_in[11];
    const float* bffn2 = (const float*)d_in[12];
    float* y = (float*)d_out;

    char* ws = (char*)d_ws;
    bf16* po   = (bf16*)(ws + 0);             // 8.4M, live to end
    bf16* h    = (bf16*)(ws + 16777216);      // h1 / attno / h2 (sequential)
    bf16* qkvb = (bf16*)(ws + 25165824);      // 24M
    bf16* vtb  = (bf16*)(ws + 50331648);      // 8M
    bf16* f1   = (bf16*)(ws + 25165824);      // alias qkv+vt (dead after attn)
    bf16* wqT  = (bf16*)(ws + 58720256);
    bf16* wpT  = (bf16*)(ws + 60293120);
    bf16* w1T  = (bf16*)(ws + 60817408);
    bf16* w2T  = (bf16*)(ws + 62914560);
    bf16* attno = h;

    k_pre<<<3328, 512, 0, stream>>>(x, ln1g, ln1b, h,
                                    wqkv, wproj, wffn1, wffn2,
                                    wqT, wpT, w1T, w2T);
    k_gemm<2, 128><<<768, 256, 0, stream>>>(h, wqT, bqkv, qkvb, vtb,
                                            nullptr, nullptr, nullptr,
                                            8192, 1536, 512);
    k_attn<<<512, 512, 0, stream>>>(qkvb, vtb, attno);
    k_gemm<0, 64><<<512, 256, 0, stream>>>(attno, wpT, bproj, po, nullptr,
                                           nullptr, nullptr, nullptr,
                                           8192, 512, 512);
    k_tln2<<<256, 512, 0, stream>>>(x, po, ln2g, ln2b, h);
    k_gemm8<<<256, 512, 0, stream>>>(h, w1T, bffn1, f1);
    k_gemm<3, 64><<<512, 256, 0, stream>>>(f1, w2T, bffn2, nullptr, nullptr,
                                           x, po, y, 8192, 512, 2048);
}